// Round 1
// baseline (875.661 us; speedup 1.0000x reference)
//
#include <hip/hip_runtime.h>
#include <math.h>

#define D_STATE 16
#define DT_RANK 6
constexpr int Bc = 2, Cc = 96, Hc = 128, Wcn = 128;
constexpr int DI = 192;      // d_inner
constexpr int Lq = 4096;     // 64*64 per quadrant
constexpr int CH = 64;       // scan chunk length
constexpr int NCH = Lq / CH; // 64 chunks

// ---------------- DCT matrix build (double precision for accuracy) ----------
__global__ void k_dct_mat(float* __restrict__ M, float* __restrict__ MT) {
    int i = blockIdx.x * blockDim.x + threadIdx.x; // 16384
    int n = i >> 7, k = i & 127;
    double v = cos(3.14159265358979323846 * (2.0 * k + 1.0) * n / 256.0) * sqrt(2.0 / 128.0);
    if (n == 0) v *= 0.70710678118654752440;
    M[n * 128 + k]  = (float)v;
    MT[k * 128 + n] = (float)v;
}

// ---------------- cosine-similarity mask ------------------------------------
__global__ void k_mask(const float* __restrict__ x, float* __restrict__ xm) {
    int b = blockIdx.y, h = blockIdx.x, w = threadIdx.x;
    const float* xb = x + (size_t)b * Cc * Hc * Wcn;
    float dot = 0.f, ss = 0.f, cs = 0.f;
    for (int c = 0; c < Cc; c++) {
        float xv = xb[(size_t)(c * Hc + h) * Wcn + w];
        float cv = xb[(size_t)(c * Hc + 64) * Wcn + 64];
        dot += xv * cv; ss += xv * xv; cs += cv * cv;
    }
    float sim = dot / (sqrtf(cs) * sqrtf(ss) + 1e-6f);
    float keep = (sim >= 0.7f) ? 1.0f : 0.0f;
    float* xo = xm + (size_t)b * Cc * Hc * Wcn;
    for (int c = 0; c < Cc; c++)
        xo[(size_t)(c * Hc + h) * Wcn + w] = keep * xb[(size_t)(c * Hc + h) * Wcn + w];
}

// ---------------- generic 128x128 left/right multiplies ---------------------
// dst[bc,i,w] = sum_j C[i*128+j] * src[bc,j,w]
__global__ void k_lmul(const float* __restrict__ C, const float* __restrict__ src, float* __restrict__ dst) {
    int bc = blockIdx.x, i = blockIdx.y, w = threadIdx.x;
    const float* s = src + (size_t)bc * 16384;
    const float* c = C + i * 128;
    float acc = 0.f;
    #pragma unroll 8
    for (int j = 0; j < 128; j++) acc += c[j] * s[j * 128 + w];
    dst[(size_t)bc * 16384 + i * 128 + w] = acc;
}
// dst[bc,h,i] = sum_j src[bc,h,j] * CT[j*128+i]
__global__ void k_rmul(const float* __restrict__ CT, const float* __restrict__ src, float* __restrict__ dst) {
    int bc = blockIdx.x, h = blockIdx.y, i = threadIdx.x;
    const float* s = src + (size_t)bc * 16384 + h * 128;
    float acc = 0.f;
    #pragma unroll 8
    for (int j = 0; j < 128; j++) acc += s[j] * CT[j * 128 + i];
    dst[(size_t)bc * 16384 + h * 128 + i] = acc;
}

// ---------------- channel LayerNorm -----------------------------------------
__global__ void k_ln(const float* __restrict__ xd, const float* __restrict__ lw,
                     const float* __restrict__ lb, float* __restrict__ xn) {
    int b = blockIdx.y, h = blockIdx.x, w = threadIdx.x;
    const float* p = xd + (size_t)b * Cc * 16384 + h * 128 + w;
    float mu = 0.f;
    for (int c = 0; c < Cc; c++) mu += p[(size_t)c * 16384];
    mu *= (1.0f / Cc);
    float var = 0.f;
    for (int c = 0; c < Cc; c++) { float d = p[(size_t)c * 16384] - mu; var += d * d; }
    var *= (1.0f / Cc);
    float inv = rsqrtf(var + 1e-5f);
    float* o = xn + (size_t)b * Cc * 16384 + h * 128 + w;
    for (int c = 0; c < Cc; c++)
        o[(size_t)c * 16384] = (p[(size_t)c * 16384] - mu) * inv * lw[c] + lb[c];
}

// ---------------- in-projection: xz[qb,e,l] = sum_c xn_q[b,c,l]*in_w[q,e,c] -
__global__ void k_inproj(const float* __restrict__ xn, const float* __restrict__ in_w,
                         float* __restrict__ xz) {
    int qb = blockIdx.z; int q = qb >> 1, b = qb & 1;
    int row = blockIdx.x, lw = threadIdx.x;
    int e = blockIdx.y * 4 + threadIdx.y;
    const float* xp = xn + ((size_t)(b * Cc) * Hc + (q >> 1) * 64 + row) * Wcn + (q & 1) * 64 + lw;
    const float* wp = in_w + ((size_t)q * 384 + e) * 96;
    float acc = 0.f;
    #pragma unroll 8
    for (int c = 0; c < Cc; c++) acc += xp[(size_t)c * Hc * Wcn] * wp[c];
    xz[((size_t)qb * 384 + e) * Lq + row * 64 + lw] = acc;
}

// ---------------- causal depthwise conv (k=4) + bias + silu -----------------
__global__ void k_conv(const float* __restrict__ xz, const float* __restrict__ cw,
                       const float* __restrict__ cb, float* __restrict__ xi) {
    int qb = blockIdx.z; int q = qb >> 1;
    int d = blockIdx.y;
    int l = blockIdx.x * 256 + threadIdx.x;
    const float* src = xz + ((size_t)qb * 384 + d) * Lq;
    const float* w = cw + (size_t)(q * DI + d) * 4;
    float acc = cb[q * DI + d];
    if (l >= 3) acc += w[0] * src[l - 3];
    if (l >= 2) acc += w[1] * src[l - 2];
    if (l >= 1) acc += w[2] * src[l - 1];
    acc += w[3] * src[l];
    xi[((size_t)qb * DI + d) * Lq + l] = acc / (1.f + expf(-acc));
}

// ---------------- x-projection: dbl[qb,j,l] = sum_d xi[qb,d,l]*xp_w[q,j,d] --
__global__ void k_xpproj(const float* __restrict__ xi, const float* __restrict__ xp_w,
                         float* __restrict__ dbl) {
    int qb = blockIdx.z; int q = qb >> 1;
    int j = blockIdx.y;
    int l = blockIdx.x * 256 + threadIdx.x;
    const float* xb = xi + (size_t)qb * DI * Lq + l;
    const float* wp = xp_w + ((size_t)q * 38 + j) * DI;
    float acc = 0.f;
    #pragma unroll 8
    for (int d = 0; d < DI; d++) acc += xb[(size_t)d * Lq] * wp[d];
    dbl[((size_t)qb * 38 + j) * Lq + l] = acc;
}

__device__ __forceinline__ float softplusf(float x) {
    return fmaxf(x, 0.f) + log1pf(expf(-fabsf(x)));
}

// ---------------- scan pass 1: per-chunk decay product + local state --------
__global__ void k_scan1(const float* __restrict__ dbl, const float* __restrict__ xi,
                        const float* __restrict__ dt_w, const float* __restrict__ dt_b,
                        const float* __restrict__ A_log,
                        float* __restrict__ P, float* __restrict__ Hl) {
    int qb = blockIdx.y; int q = qb >> 1;
    int ch = blockIdx.x;
    int d = threadIdx.x;
    float A[16], Pr[16], h[16];
    #pragma unroll
    for (int s = 0; s < 16; s++) {
        A[s] = -expf(A_log[((size_t)(q * DI + d)) * 16 + s]);
        Pr[s] = 1.f; h[s] = 0.f;
    }
    float dw[6];
    #pragma unroll
    for (int r = 0; r < 6; r++) dw[r] = dt_w[(size_t)(q * DI + d) * 6 + r];
    float db = dt_b[q * DI + d];
    const float* dblb = dbl + (size_t)qb * 38 * Lq;
    const float* xib = xi + ((size_t)qb * DI + d) * Lq;
    for (int i = 0; i < CH; i++) {
        int l = ch * CH + i;
        float t = db;
        #pragma unroll
        for (int r = 0; r < 6; r++) t += dblb[(size_t)r * Lq + l] * dw[r];
        float delta = softplusf(t);
        float dx = delta * xib[l];
        #pragma unroll
        for (int s = 0; s < 16; s++) {
            float dA = expf(delta * A[s]);
            float Bm = dblb[(size_t)(6 + s) * Lq + l];
            h[s] = dA * h[s] + dx * Bm;
            Pr[s] *= dA;
        }
    }
    size_t base = ((size_t)qb * NCH + ch) * 16;
    #pragma unroll
    for (int s = 0; s < 16; s++) {
        P[(base + s) * DI + d]  = Pr[s];
        Hl[(base + s) * DI + d] = h[s];
    }
}

// ---------------- scan pass 2: serial recombination over chunks -------------
__global__ void k_scan2(const float* __restrict__ P, const float* __restrict__ Hl,
                        float* __restrict__ carry) {
    int t = blockIdx.x * 256 + threadIdx.x;   // qb*3072 + s*192 + d
    int qb = t / (16 * DI);
    int sd = t % (16 * DI);
    float c = 0.f;
    for (int ch = 0; ch < NCH; ch++) {
        size_t idx = (size_t)(qb * NCH + ch) * (16 * DI) + sd;
        carry[idx] = c;
        c = P[idx] * c + Hl[idx];
    }
}

// ---------------- scan pass 3: seeded rerun + y + gating --------------------
__global__ void k_scan3(const float* __restrict__ dbl, const float* __restrict__ xi,
                        const float* __restrict__ xz,
                        const float* __restrict__ dt_w, const float* __restrict__ dt_b,
                        const float* __restrict__ A_log, const float* __restrict__ Dp,
                        const float* __restrict__ carry, float* __restrict__ yg) {
    int qb = blockIdx.y; int q = qb >> 1;
    int ch = blockIdx.x;
    int d = threadIdx.x;
    float A[16], h[16];
    size_t cbase = (size_t)(qb * NCH + ch) * (16 * DI) + d;
    #pragma unroll
    for (int s = 0; s < 16; s++) {
        A[s] = -expf(A_log[((size_t)(q * DI + d)) * 16 + s]);
        h[s] = carry[cbase + (size_t)s * DI];
    }
    float dw[6];
    #pragma unroll
    for (int r = 0; r < 6; r++) dw[r] = dt_w[(size_t)(q * DI + d) * 6 + r];
    float db = dt_b[q * DI + d];
    float dpv = Dp[q * DI + d];
    const float* dblb = dbl + (size_t)qb * 38 * Lq;
    const float* xib = xi + ((size_t)qb * DI + d) * Lq;
    const float* zb = xz + ((size_t)qb * 384 + DI + d) * Lq;
    for (int i = 0; i < CH; i++) {
        int l = ch * CH + i;
        float t = db;
        #pragma unroll
        for (int r = 0; r < 6; r++) t += dblb[(size_t)r * Lq + l] * dw[r];
        float delta = softplusf(t);
        float xiv = xib[l];
        float dx = delta * xiv;
        float y = 0.f;
        #pragma unroll
        for (int s = 0; s < 16; s++) {
            float dA = expf(delta * A[s]);
            float Bm = dblb[(size_t)(6 + s) * Lq + l];
            h[s] = dA * h[s] + dx * Bm;
            y += h[s] * dblb[(size_t)(22 + s) * Lq + l];
        }
        y += xiv * dpv;
        float zv = zb[l];
        y *= zv / (1.f + expf(-zv));
        yg[((size_t)qb * Lq + l) * DI + d] = y;
    }
}

// ---------------- out-projection + residual add into xd ---------------------
__global__ void k_outproj(const float* __restrict__ yg, const float* __restrict__ out_w,
                          float* __restrict__ xd) {
    __shared__ float ys[64][DI + 1];
    int qb = blockIdx.y; int q = qb >> 1, b = qb & 1;
    int row = blockIdx.x;
    int tid = threadIdx.y * 64 + threadIdx.x;
    const float* yb = yg + ((size_t)qb * Lq + row * 64) * DI;
    for (int i = tid; i < 64 * DI; i += 256) ys[i / DI][i % DI] = yb[i];
    __syncthreads();
    int lw = threadIdx.x;
    for (int c = threadIdx.y; c < Cc; c += 4) {
        const float* wp = out_w + ((size_t)q * Cc + c) * DI;
        float acc = 0.f;
        #pragma unroll 8
        for (int d = 0; d < DI; d++) acc += ys[lw][d] * wp[d];
        size_t o = ((size_t)(b * Cc + c) * Hc + (q >> 1) * 64 + row) * Wcn + (q & 1) * 64 + lw;
        xd[o] += acc;
    }
}

extern "C" void kernel_launch(void* const* d_in, const int* in_sizes, int n_in,
                              void* d_out, int out_size, void* d_ws, size_t ws_size,
                              hipStream_t stream) {
    const float* x     = (const float*)d_in[0];
    const float* ln_w  = (const float*)d_in[1];
    const float* ln_b  = (const float*)d_in[2];
    const float* in_w  = (const float*)d_in[3];
    const float* cw    = (const float*)d_in[4];
    const float* cb    = (const float*)d_in[5];
    const float* xp_w  = (const float*)d_in[6];
    const float* dt_w  = (const float*)d_in[7];
    const float* dt_b  = (const float*)d_in[8];
    const float* A_log = (const float*)d_in[9];
    const float* Dp    = (const float*)d_in[10];
    const float* out_w = (const float*)d_in[11];
    float* out = (float*)d_out;

    float* ws = (float*)d_ws;
    const size_t NPIX = (size_t)Bc * Cc * Hc * Wcn;      // 3,145,728
    float* M   = ws;                 // 16384
    float* MT  = M + 16384;          // 16384
    float* xm  = MT + 16384;         // NPIX (reused as xn)
    float* tmp = xm + NPIX;          // NPIX (reused as t2)
    float* xd  = tmp + NPIX;         // NPIX
    float* xz  = xd + NPIX;          // 8*384*4096 = 12,582,912
    float* xi  = xz + (size_t)8 * 384 * Lq;   // 6,291,456
    float* dbl = xi + (size_t)8 * DI * Lq;    // 1,245,184
    float* P   = dbl + (size_t)8 * 38 * Lq;   // 1,572,864
    float* Hl  = P + (size_t)8 * NCH * 16 * DI;
    float* cy  = Hl + (size_t)8 * NCH * 16 * DI;
    float* yg  = cy + (size_t)8 * NCH * 16 * DI;  // 6,291,456

    k_dct_mat<<<128, 128, 0, stream>>>(M, MT);
    k_mask<<<dim3(Hc, Bc), Wcn, 0, stream>>>(x, xm);
    k_lmul<<<dim3(Bc * Cc, 128), 128, 0, stream>>>(M, xm, tmp);     // DCT rows
    k_rmul<<<dim3(Bc * Cc, 128), 128, 0, stream>>>(MT, tmp, xd);    // DCT cols
    k_ln<<<dim3(Hc, Bc), Wcn, 0, stream>>>(xd, ln_w, ln_b, xm);     // xn into xm
    k_inproj<<<dim3(64, 96, 8), dim3(64, 4), 0, stream>>>(xm, in_w, xz);
    k_conv<<<dim3(16, DI, 8), 256, 0, stream>>>(xz, cw, cb, xi);
    k_xpproj<<<dim3(16, 38, 8), 256, 0, stream>>>(xi, xp_w, dbl);
    k_scan1<<<dim3(NCH, 8), DI, 0, stream>>>(dbl, xi, dt_w, dt_b, A_log, P, Hl);
    k_scan2<<<96, 256, 0, stream>>>(P, Hl, cy);
    k_scan3<<<dim3(NCH, 8), DI, 0, stream>>>(dbl, xi, xz, dt_w, dt_b, A_log, Dp, cy, yg);
    k_outproj<<<dim3(64, 8), dim3(64, 4), 0, stream>>>(yg, out_w, xd);
    k_rmul<<<dim3(Bc * Cc, 128), 128, 0, stream>>>(M, xd, tmp);     // iDCT cols
    k_lmul<<<dim3(Bc * Cc, 128), 128, 0, stream>>>(MT, tmp, out);   // iDCT rows
}

// Round 2
// 425.576 us; speedup vs baseline: 2.0576x; 2.0576x over previous
//
#include <hip/hip_runtime.h>
#include <math.h>

#define D_STATE 16
#define DT_RANK 6
constexpr int Bc = 2, Cc = 96, Hc = 128, Wcn = 128;
constexpr int DI = 192;      // d_inner
constexpr int Lq = 4096;     // 64*64 per quadrant
constexpr int CH = 64;       // scan chunk length
constexpr int NCH = Lq / CH; // 64 chunks

// ---------------- DCT matrix build (double precision for accuracy) ----------
__global__ void k_dct_mat(float* __restrict__ M, float* __restrict__ MT) {
    int i = blockIdx.x * blockDim.x + threadIdx.x; // 16384
    int n = i >> 7, k = i & 127;
    double v = cos(3.14159265358979323846 * (2.0 * k + 1.0) * n / 256.0) * sqrt(2.0 / 128.0);
    if (n == 0) v *= 0.70710678118654752440;
    M[n * 128 + k]  = (float)v;
    MT[k * 128 + n] = (float)v;
}

// ---------------- cosine-similarity mask ------------------------------------
__global__ void k_mask(const float* __restrict__ x, float* __restrict__ xm) {
    int b = blockIdx.y, h = blockIdx.x, w = threadIdx.x;
    const float* xb = x + (size_t)b * Cc * Hc * Wcn;
    float dot = 0.f, ss = 0.f, cs = 0.f;
    for (int c = 0; c < Cc; c++) {
        float xv = xb[(size_t)(c * Hc + h) * Wcn + w];
        float cv = xb[(size_t)(c * Hc + 64) * Wcn + 64];
        dot += xv * cv; ss += xv * xv; cs += cv * cv;
    }
    float sim = dot / (sqrtf(cs) * sqrtf(ss) + 1e-6f);
    float keep = (sim >= 0.7f) ? 1.0f : 0.0f;
    float* xo = xm + (size_t)b * Cc * Hc * Wcn;
    for (int c = 0; c < Cc; c++)
        xo[(size_t)(c * Hc + h) * Wcn + w] = keep * xb[(size_t)(c * Hc + h) * Wcn + w];
}

// ---------------- generic tiled 128x128x128 GEMM: D[r][n] = sum_j L[r][j]R[j][n]
// row strides all 128; D batch stride 16384. 64x64 tile, K split 2x64.
__global__ void k_g128(const float* __restrict__ L, size_t lb,
                       const float* __restrict__ R, size_t rb,
                       float* __restrict__ D) {
    __shared__ float Ls[64][68];
    __shared__ float Rs[64][68];
    int bc = blockIdx.x;
    int r0 = blockIdx.y * 64, n0 = blockIdx.z * 64;
    const float* Lp = L + lb * bc;
    const float* Rp = R + rb * bc;
    float* Dq = D + (size_t)bc * 16384;
    int tid = threadIdx.x;
    int tx = tid & 15, ty = tid >> 4;
    float acc[4][4] = {};
    for (int ks = 0; ks < 2; ks++) {
        __syncthreads();
        #pragma unroll
        for (int i = 0; i < 4; i++) {
            int idx = i * 256 + tid;          // 0..1023
            int row = idx >> 4, quad = idx & 15;
            float4 lv = *(const float4*)(Lp + (size_t)(r0 + row) * 128 + ks * 64 + quad * 4);
            *(float4*)&Ls[row][quad * 4] = lv;
            float4 rv = *(const float4*)(Rp + (size_t)(ks * 64 + row) * 128 + n0 + quad * 4);
            *(float4*)&Rs[row][quad * 4] = rv;
        }
        __syncthreads();
        #pragma unroll 8
        for (int j = 0; j < 64; j++) {
            float a0 = Ls[ty][j], a1 = Ls[ty + 16][j], a2 = Ls[ty + 32][j], a3 = Ls[ty + 48][j];
            float4 bv = *(float4*)&Rs[j][tx * 4];
            acc[0][0] += a0 * bv.x; acc[0][1] += a0 * bv.y; acc[0][2] += a0 * bv.z; acc[0][3] += a0 * bv.w;
            acc[1][0] += a1 * bv.x; acc[1][1] += a1 * bv.y; acc[1][2] += a1 * bv.z; acc[1][3] += a1 * bv.w;
            acc[2][0] += a2 * bv.x; acc[2][1] += a2 * bv.y; acc[2][2] += a2 * bv.z; acc[2][3] += a2 * bv.w;
            acc[3][0] += a3 * bv.x; acc[3][1] += a3 * bv.y; acc[3][2] += a3 * bv.z; acc[3][3] += a3 * bv.w;
        }
    }
    #pragma unroll
    for (int i = 0; i < 4; i++) {
        float4 v = make_float4(acc[i][0], acc[i][1], acc[i][2], acc[i][3]);
        *(float4*)(Dq + (size_t)(r0 + ty + 16 * i) * 128 + n0 + tx * 4) = v;
    }
}

// ---------------- in-projection, LN fused: xz[qb,e,l] = sum_c LN(xd)[c,l]*in_w[q,e,c]
__global__ void k_inproj_t(const float* __restrict__ xd, const float* __restrict__ in_w,
                           const float* __restrict__ lnw, const float* __restrict__ lnb,
                           float* __restrict__ xz) {
    __shared__ float Ws[64][100];   // e-tile 64 x K=96
    __shared__ float Xs[96][68];    // c 96 x l-tile 64
    __shared__ float mu[64], inv[64], lws[96], lbs[96];
    int lt = blockIdx.x;            // 64 l-tiles (= quadrant row)
    int et = blockIdx.y;            // 6 e-tiles
    int qb = blockIdx.z; int q = qb >> 1, b = qb & 1;
    int qr = q >> 1, qc = q & 1;
    int tid = threadIdx.x, tx = tid & 15, ty = tid >> 4;
    if (tid < 96) { lws[tid] = lnw[tid]; lbs[tid] = lnb[tid]; }
    #pragma unroll
    for (int i = 0; i < 6; i++) {   // Ws: 64 rows x 24 float4
        int idx = i * 256 + tid; int e = idx / 24, kq = idx % 24;
        float4 v = *(const float4*)(in_w + ((size_t)(q * 384 + et * 64 + e)) * 96 + kq * 4);
        *(float4*)&Ws[e][kq * 4] = v;
    }
    const float* xb = xd + ((size_t)(b * Cc) * Hc + qr * 64 + lt) * Wcn + qc * 64;
    #pragma unroll
    for (int i = 0; i < 6; i++) {   // Xs: 96 rows x 16 float4
        int idx = i * 256 + tid; int c = idx >> 4, tq = idx & 15;
        float4 v = *(const float4*)(xb + (size_t)c * Hc * Wcn + tq * 4);
        *(float4*)&Xs[c][tq * 4] = v;
    }
    __syncthreads();
    if (tid < 64) {                 // LN stats per column l
        float m = 0.f;
        for (int c = 0; c < 96; c++) m += Xs[c][tid];
        m *= (1.0f / 96.0f);
        float v = 0.f;
        for (int c = 0; c < 96; c++) { float d = Xs[c][tid] - m; v += d * d; }
        mu[tid] = m; inv[tid] = rsqrtf(v * (1.0f / 96.0f) + 1e-5f);
    }
    __syncthreads();
    #pragma unroll
    for (int i = 0; i < 24; i++) {  // normalize in place
        int idx = i * 256 + tid; int c = idx >> 6, l = idx & 63;
        Xs[c][l] = (Xs[c][l] - mu[l]) * inv[l] * lws[c] + lbs[c];
    }
    __syncthreads();
    float acc[4][4] = {};
    #pragma unroll 8
    for (int k = 0; k < 96; k++) {
        float a0 = Ws[ty][k], a1 = Ws[ty + 16][k], a2 = Ws[ty + 32][k], a3 = Ws[ty + 48][k];
        float4 bv = *(float4*)&Xs[k][tx * 4];
        acc[0][0] += a0 * bv.x; acc[0][1] += a0 * bv.y; acc[0][2] += a0 * bv.z; acc[0][3] += a0 * bv.w;
        acc[1][0] += a1 * bv.x; acc[1][1] += a1 * bv.y; acc[1][2] += a1 * bv.z; acc[1][3] += a1 * bv.w;
        acc[2][0] += a2 * bv.x; acc[2][1] += a2 * bv.y; acc[2][2] += a2 * bv.z; acc[2][3] += a2 * bv.w;
        acc[3][0] += a3 * bv.x; acc[3][1] += a3 * bv.y; acc[3][2] += a3 * bv.z; acc[3][3] += a3 * bv.w;
    }
    #pragma unroll
    for (int i = 0; i < 4; i++) {
        float4 v = make_float4(acc[i][0], acc[i][1], acc[i][2], acc[i][3]);
        *(float4*)(xz + ((size_t)qb * 384 + et * 64 + ty + 16 * i) * Lq + lt * 64 + tx * 4) = v;
    }
}

// ---------------- causal depthwise conv (k=4) + bias + silu -----------------
__global__ void k_conv(const float* __restrict__ xz, const float* __restrict__ cw,
                       const float* __restrict__ cb, float* __restrict__ xi) {
    int qb = blockIdx.z; int q = qb >> 1;
    int d = blockIdx.y;
    int l = blockIdx.x * 256 + threadIdx.x;
    const float* src = xz + ((size_t)qb * 384 + d) * Lq;
    const float* w = cw + (size_t)(q * DI + d) * 4;
    float acc = cb[q * DI + d];
    if (l >= 3) acc += w[0] * src[l - 3];
    if (l >= 2) acc += w[1] * src[l - 2];
    if (l >= 1) acc += w[2] * src[l - 1];
    acc += w[3] * src[l];
    xi[((size_t)qb * DI + d) * Lq + l] = acc / (1.f + expf(-acc));
}

// ---------------- x-projection: 2-j x 2-l register blocked -------------------
__global__ void k_xpproj(const float* __restrict__ xi, const float* __restrict__ xp_w,
                         float* __restrict__ dbl) {
    int qb = blockIdx.z; int q = qb >> 1;
    int j0 = blockIdx.y * 2;
    int l2 = blockIdx.x * 256 + threadIdx.x;    // pair index 0..2047
    const float* xb = xi + (size_t)qb * DI * Lq + l2 * 2;
    const float* w0 = xp_w + ((size_t)q * 38 + j0) * DI;
    const float* w1 = w0 + DI;
    float2 a0 = make_float2(0.f, 0.f), a1 = make_float2(0.f, 0.f);
    #pragma unroll 8
    for (int d = 0; d < DI; d++) {
        float2 xv = *(const float2*)(xb + (size_t)d * Lq);
        float ww0 = w0[d], ww1 = w1[d];
        a0.x += ww0 * xv.x; a0.y += ww0 * xv.y;
        a1.x += ww1 * xv.x; a1.y += ww1 * xv.y;
    }
    *(float2*)(dbl + ((size_t)qb * 38 + j0) * Lq + l2 * 2) = a0;
    *(float2*)(dbl + ((size_t)qb * 38 + j0 + 1) * Lq + l2 * 2) = a1;
}

__device__ __forceinline__ float softplusf(float x) {
    return fmaxf(x, 0.f) + log1pf(expf(-fabsf(x)));
}

// ---------------- scan pass 1: per-chunk decay product + local state --------
__global__ void k_scan1(const float* __restrict__ dbl, const float* __restrict__ xi,
                        const float* __restrict__ dt_w, const float* __restrict__ dt_b,
                        const float* __restrict__ A_log,
                        float* __restrict__ P, float* __restrict__ Hl) {
    int qb = blockIdx.y; int q = qb >> 1;
    int ch = blockIdx.x;
    int d = threadIdx.x;
    float A[16], Pr[16], h[16];
    #pragma unroll
    for (int s = 0; s < 16; s++) {
        A[s] = -expf(A_log[((size_t)(q * DI + d)) * 16 + s]);
        Pr[s] = 1.f; h[s] = 0.f;
    }
    float dw[6];
    #pragma unroll
    for (int r = 0; r < 6; r++) dw[r] = dt_w[(size_t)(q * DI + d) * 6 + r];
    float db = dt_b[q * DI + d];
    const float* dblb = dbl + (size_t)qb * 38 * Lq;
    const float* xib = xi + ((size_t)qb * DI + d) * Lq;
    for (int i = 0; i < CH; i++) {
        int l = ch * CH + i;
        float t = db;
        #pragma unroll
        for (int r = 0; r < 6; r++) t += dblb[(size_t)r * Lq + l] * dw[r];
        float delta = softplusf(t);
        float dx = delta * xib[l];
        #pragma unroll
        for (int s = 0; s < 16; s++) {
            float dA = expf(delta * A[s]);
            float Bm = dblb[(size_t)(6 + s) * Lq + l];
            h[s] = dA * h[s] + dx * Bm;
            Pr[s] *= dA;
        }
    }
    size_t base = ((size_t)qb * NCH + ch) * 16;
    #pragma unroll
    for (int s = 0; s < 16; s++) {
        P[(base + s) * DI + d]  = Pr[s];
        Hl[(base + s) * DI + d] = h[s];
    }
}

// ---------------- scan pass 2: serial recombination over chunks -------------
__global__ void k_scan2(const float* __restrict__ P, const float* __restrict__ Hl,
                        float* __restrict__ carry) {
    int t = blockIdx.x * 256 + threadIdx.x;   // qb*3072 + s*192 + d
    int qb = t / (16 * DI);
    int sd = t % (16 * DI);
    float c = 0.f;
    for (int ch = 0; ch < NCH; ch++) {
        size_t idx = (size_t)(qb * NCH + ch) * (16 * DI) + sd;
        carry[idx] = c;
        c = P[idx] * c + Hl[idx];
    }
}

// ---------------- scan pass 3: seeded rerun + y + gate; yg in [d][l] layout -
__global__ void k_scan3(const float* __restrict__ dbl, const float* __restrict__ xi,
                        const float* __restrict__ xz,
                        const float* __restrict__ dt_w, const float* __restrict__ dt_b,
                        const float* __restrict__ A_log, const float* __restrict__ Dp,
                        const float* __restrict__ carry, float* __restrict__ yg) {
    __shared__ float yt[DI][65];
    int qb = blockIdx.y; int q = qb >> 1;
    int ch = blockIdx.x;
    int d = threadIdx.x;
    float A[16], h[16];
    size_t cbase = (size_t)(qb * NCH + ch) * (16 * DI) + d;
    #pragma unroll
    for (int s = 0; s < 16; s++) {
        A[s] = -expf(A_log[((size_t)(q * DI + d)) * 16 + s]);
        h[s] = carry[cbase + (size_t)s * DI];
    }
    float dw[6];
    #pragma unroll
    for (int r = 0; r < 6; r++) dw[r] = dt_w[(size_t)(q * DI + d) * 6 + r];
    float db = dt_b[q * DI + d];
    float dpv = Dp[q * DI + d];
    const float* dblb = dbl + (size_t)qb * 38 * Lq;
    const float* xib = xi + ((size_t)qb * DI + d) * Lq;
    const float* zb = xz + ((size_t)qb * 384 + DI + d) * Lq;
    for (int i = 0; i < CH; i++) {
        int l = ch * CH + i;
        float t = db;
        #pragma unroll
        for (int r = 0; r < 6; r++) t += dblb[(size_t)r * Lq + l] * dw[r];
        float delta = softplusf(t);
        float xiv = xib[l];
        float dx = delta * xiv;
        float y = 0.f;
        #pragma unroll
        for (int s = 0; s < 16; s++) {
            float dA = expf(delta * A[s]);
            float Bm = dblb[(size_t)(6 + s) * Lq + l];
            h[s] = dA * h[s] + dx * Bm;
            y += h[s] * dblb[(size_t)(22 + s) * Lq + l];
        }
        y += xiv * dpv;
        float zv = zb[l];
        y *= zv / (1.f + expf(-zv));
        yt[d][i] = y;
    }
    __syncthreads();
    // transposed write-out: yg[d][l], coalesced over l
    for (int i = 0; i < 64; i++) {
        int row = i * 3 + (d >> 6);      // 0..191
        int col = d & 63;
        yg[((size_t)qb * DI + row) * Lq + ch * CH + col] = yt[row][col];
    }
}

// ---------------- out-projection (tiled) + residual add into xd -------------
__global__ void k_outproj_t(const float* __restrict__ yg, const float* __restrict__ out_w,
                            float* __restrict__ xd) {
    __shared__ float Ws2[48][52];    // c-tile 48 x k-chunk 48
    __shared__ float Ys[48][132];    // k-chunk 48 x l-tile 128
    int lt = blockIdx.x;             // 32 l-tiles of 128
    int ct = blockIdx.y;             // 2 c-tiles of 48
    int qb = blockIdx.z; int q = qb >> 1, b = qb & 1;
    int qr = q >> 1, qc = q & 1;
    int tid = threadIdx.x, tx = tid & 15, ty = tid >> 4;
    float acc[3][2][4] = {};
    for (int ks = 0; ks < 4; ks++) {
        __syncthreads();
        #pragma unroll
        for (int i = 0; i < 3; i++) {    // Ws2: 48 rows x 12 float4 = 576
            int idx = i * 256 + tid;
            if (idx < 576) {
                int row = idx / 12, q4 = idx % 12;
                float4 v = *(const float4*)(out_w + ((size_t)(q * Cc + ct * 48 + row)) * DI + ks * 48 + q4 * 4);
                *(float4*)&Ws2[row][q4 * 4] = v;
            }
        }
        #pragma unroll
        for (int i = 0; i < 6; i++) {    // Ys: 48 rows x 32 float4 = 1536
            int idx = i * 256 + tid;
            int kk = idx >> 5, q4 = idx & 31;
            float4 v = *(const float4*)(yg + ((size_t)qb * DI + ks * 48 + kk) * Lq + lt * 128 + q4 * 4);
            *(float4*)&Ys[kk][q4 * 4] = v;
        }
        __syncthreads();
        #pragma unroll 4
        for (int kk = 0; kk < 48; kk++) {
            float w0 = Ws2[ty][kk], w1 = Ws2[ty + 16][kk], w2 = Ws2[ty + 32][kk];
            float4 y0 = *(float4*)&Ys[kk][tx * 4];
            float4 y1 = *(float4*)&Ys[kk][tx * 4 + 64];
            acc[0][0][0] += w0 * y0.x; acc[0][0][1] += w0 * y0.y; acc[0][0][2] += w0 * y0.z; acc[0][0][3] += w0 * y0.w;
            acc[0][1][0] += w0 * y1.x; acc[0][1][1] += w0 * y1.y; acc[0][1][2] += w0 * y1.z; acc[0][1][3] += w0 * y1.w;
            acc[1][0][0] += w1 * y0.x; acc[1][0][1] += w1 * y0.y; acc[1][0][2] += w1 * y0.z; acc[1][0][3] += w1 * y0.w;
            acc[1][1][0] += w1 * y1.x; acc[1][1][1] += w1 * y1.y; acc[1][1][2] += w1 * y1.z; acc[1][1][3] += w1 * y1.w;
            acc[2][0][0] += w2 * y0.x; acc[2][0][1] += w2 * y0.y; acc[2][0][2] += w2 * y0.z; acc[2][0][3] += w2 * y0.w;
            acc[2][1][0] += w2 * y1.x; acc[2][1][1] += w2 * y1.y; acc[2][1][2] += w2 * y1.z; acc[2][1][3] += w2 * y1.w;
        }
    }
    #pragma unroll
    for (int i = 0; i < 3; i++) {
        int c = ct * 48 + ty + 16 * i;
        #pragma unroll
        for (int s = 0; s < 2; s++) {
            float* p = xd + (((size_t)(b * Cc + c) * Hc) + qr * 64 + lt * 2 + s) * Wcn + qc * 64 + tx * 4;
            float4 v = *(float4*)p;
            v.x += acc[i][s][0]; v.y += acc[i][s][1]; v.z += acc[i][s][2]; v.w += acc[i][s][3];
            *(float4*)p = v;
        }
    }
}

extern "C" void kernel_launch(void* const* d_in, const int* in_sizes, int n_in,
                              void* d_out, int out_size, void* d_ws, size_t ws_size,
                              hipStream_t stream) {
    const float* x     = (const float*)d_in[0];
    const float* ln_w  = (const float*)d_in[1];
    const float* ln_b  = (const float*)d_in[2];
    const float* in_w  = (const float*)d_in[3];
    const float* cw    = (const float*)d_in[4];
    const float* cb    = (const float*)d_in[5];
    const float* xp_w  = (const float*)d_in[6];
    const float* dt_w  = (const float*)d_in[7];
    const float* dt_b  = (const float*)d_in[8];
    const float* A_log = (const float*)d_in[9];
    const float* Dp    = (const float*)d_in[10];
    const float* out_w = (const float*)d_in[11];
    float* out = (float*)d_out;

    float* ws = (float*)d_ws;
    const size_t NPIX = (size_t)Bc * Cc * Hc * Wcn;      // 3,145,728
    float* M   = ws;                 // 16384
    float* MT  = M + 16384;          // 16384
    float* xm  = MT + 16384;         // NPIX
    float* tmp = xm + NPIX;          // NPIX
    float* xd  = tmp + NPIX;         // NPIX
    float* xz  = xd + NPIX;          // 8*384*4096
    float* xi  = xz + (size_t)8 * 384 * Lq;
    float* dbl = xi + (size_t)8 * DI * Lq;
    float* P   = dbl + (size_t)8 * 38 * Lq;
    float* Hl  = P + (size_t)8 * NCH * 16 * DI;
    float* cy  = Hl + (size_t)8 * NCH * 16 * DI;
    float* yg  = cy + (size_t)8 * NCH * 16 * DI;

    k_dct_mat<<<128, 128, 0, stream>>>(M, MT);
    k_mask<<<dim3(Hc, Bc), Wcn, 0, stream>>>(x, xm);
    // DCT: tmp = M * xm ; xd = tmp * MT  (right-mul by MT == L=tmp, R=MT)
    k_g128<<<dim3(192, 2, 2), 256, 0, stream>>>(M, 0, xm, 16384, tmp);
    k_g128<<<dim3(192, 2, 2), 256, 0, stream>>>(tmp, 16384, MT, 0, xd);
    k_inproj_t<<<dim3(64, 6, 8), 256, 0, stream>>>(xd, in_w, ln_w, ln_b, xz);
    k_conv<<<dim3(16, DI, 8), 256, 0, stream>>>(xz, cw, cb, xi);
    k_xpproj<<<dim3(8, 19, 8), 256, 0, stream>>>(xi, xp_w, dbl);
    k_scan1<<<dim3(NCH, 8), DI, 0, stream>>>(dbl, xi, dt_w, dt_b, A_log, P, Hl);
    k_scan2<<<96, 256, 0, stream>>>(P, Hl, cy);
    k_scan3<<<dim3(NCH, 8), DI, 0, stream>>>(dbl, xi, xz, dt_w, dt_b, A_log, Dp, cy, yg);
    k_outproj_t<<<dim3(32, 2, 8), 256, 0, stream>>>(yg, out_w, xd);
    // iDCT: tmp = xd * M ; out = MT * tmp
    k_g128<<<dim3(192, 2, 2), 256, 0, stream>>>(xd, 16384, M, 0, tmp);
    k_g128<<<dim3(192, 2, 2), 256, 0, stream>>>(MT, 0, tmp, 16384, out);
}

// Round 3
// 360.943 us; speedup vs baseline: 2.4260x; 1.1791x over previous
//
#include <hip/hip_runtime.h>
#include <math.h>

#define D_STATE 16
#define DT_RANK 6
constexpr int Bc = 2, Cc = 96, Hc = 128, Wcn = 128;
constexpr int DI = 192;       // d_inner
constexpr int Lq = 4096;      // 64*64 per quadrant
constexpr int CH = 16;        // scan chunk length
constexpr int NCH = Lq / CH;  // 256 chunks

// ---------------- DCT matrix build ------------------------------------------
__global__ void k_dct_mat(float* __restrict__ M, float* __restrict__ MT) {
    int i = blockIdx.x * blockDim.x + threadIdx.x; // 16384
    int n = i >> 7, k = i & 127;
    double v = cos(3.14159265358979323846 * (2.0 * k + 1.0) * n / 256.0) * sqrt(2.0 / 128.0);
    if (n == 0) v *= 0.70710678118654752440;
    M[n * 128 + k]  = (float)v;
    MT[k * 128 + n] = (float)v;
}

// ---------------- cosine-similarity mask ------------------------------------
__global__ void k_mask(const float* __restrict__ x, float* __restrict__ xm) {
    int b = blockIdx.y, h = blockIdx.x, w = threadIdx.x;
    const float* xb = x + (size_t)b * Cc * Hc * Wcn;
    float dot = 0.f, ss = 0.f, cs = 0.f;
    for (int c = 0; c < Cc; c++) {
        float xv = xb[(size_t)(c * Hc + h) * Wcn + w];
        float cv = xb[(size_t)(c * Hc + 64) * Wcn + 64];
        dot += xv * cv; ss += xv * xv; cs += cv * cv;
    }
    float sim = dot / (sqrtf(cs) * sqrtf(ss) + 1e-6f);
    float keep = (sim >= 0.7f) ? 1.0f : 0.0f;
    float* xo = xm + (size_t)b * Cc * Hc * Wcn;
    for (int c = 0; c < Cc; c++)
        xo[(size_t)(c * Hc + h) * Wcn + w] = keep * xb[(size_t)(c * Hc + h) * Wcn + w];
}

// ---------------- generic tiled 128x128x128 GEMM ----------------------------
__global__ void k_g128(const float* __restrict__ L, size_t lb,
                       const float* __restrict__ R, size_t rb,
                       float* __restrict__ D) {
    __shared__ float Ls[64][68];
    __shared__ float Rs[64][68];
    int bc = blockIdx.x;
    int r0 = blockIdx.y * 64, n0 = blockIdx.z * 64;
    const float* Lp = L + lb * bc;
    const float* Rp = R + rb * bc;
    float* Dq = D + (size_t)bc * 16384;
    int tid = threadIdx.x;
    int tx = tid & 15, ty = tid >> 4;
    float acc[4][4] = {};
    for (int ks = 0; ks < 2; ks++) {
        __syncthreads();
        #pragma unroll
        for (int i = 0; i < 4; i++) {
            int idx = i * 256 + tid;
            int row = idx >> 4, quad = idx & 15;
            float4 lv = *(const float4*)(Lp + (size_t)(r0 + row) * 128 + ks * 64 + quad * 4);
            *(float4*)&Ls[row][quad * 4] = lv;
            float4 rv = *(const float4*)(Rp + (size_t)(ks * 64 + row) * 128 + n0 + quad * 4);
            *(float4*)&Rs[row][quad * 4] = rv;
        }
        __syncthreads();
        #pragma unroll 8
        for (int j = 0; j < 64; j++) {
            float a0 = Ls[ty][j], a1 = Ls[ty + 16][j], a2 = Ls[ty + 32][j], a3 = Ls[ty + 48][j];
            float4 bv = *(float4*)&Rs[j][tx * 4];
            acc[0][0] += a0 * bv.x; acc[0][1] += a0 * bv.y; acc[0][2] += a0 * bv.z; acc[0][3] += a0 * bv.w;
            acc[1][0] += a1 * bv.x; acc[1][1] += a1 * bv.y; acc[1][2] += a1 * bv.z; acc[1][3] += a1 * bv.w;
            acc[2][0] += a2 * bv.x; acc[2][1] += a2 * bv.y; acc[2][2] += a2 * bv.z; acc[2][3] += a2 * bv.w;
            acc[3][0] += a3 * bv.x; acc[3][1] += a3 * bv.y; acc[3][2] += a3 * bv.z; acc[3][3] += a3 * bv.w;
        }
    }
    #pragma unroll
    for (int i = 0; i < 4; i++) {
        float4 v = make_float4(acc[i][0], acc[i][1], acc[i][2], acc[i][3]);
        *(float4*)(Dq + (size_t)(r0 + ty + 16 * i) * 128 + n0 + tx * 4) = v;
    }
}

// ---------------- in-projection, LN fused -----------------------------------
// et<3: xz[qb][e][l]  (x half, conv input);  et>=3: zt[qb][l][d] transposed
__global__ void k_inproj_t(const float* __restrict__ xd, const float* __restrict__ in_w,
                           const float* __restrict__ lnw, const float* __restrict__ lnb,
                           float* __restrict__ xz, float* __restrict__ zt) {
    __shared__ float Ws[64][100];   // e-tile 64 x K=96  (reused as transpose buf)
    __shared__ float Xs[96][68];    // c 96 x l-tile 64
    __shared__ float mu[64], inv[64], lws[96], lbs[96];
    int lt = blockIdx.x;            // 64 l-tiles (quadrant row)
    int et = blockIdx.y;            // 6 e-tiles
    int qb = blockIdx.z; int q = qb >> 1, b = qb & 1;
    int qr = q >> 1, qc = q & 1;
    int tid = threadIdx.x, tx = tid & 15, ty = tid >> 4;
    if (tid < 96) { lws[tid] = lnw[tid]; lbs[tid] = lnb[tid]; }
    #pragma unroll
    for (int i = 0; i < 6; i++) {
        int idx = i * 256 + tid; int e = idx / 24, kq = idx % 24;
        float4 v = *(const float4*)(in_w + ((size_t)(q * 384 + et * 64 + e)) * 96 + kq * 4);
        *(float4*)&Ws[e][kq * 4] = v;
    }
    const float* xb = xd + ((size_t)(b * Cc) * Hc + qr * 64 + lt) * Wcn + qc * 64;
    #pragma unroll
    for (int i = 0; i < 6; i++) {
        int idx = i * 256 + tid; int c = idx >> 4, tq = idx & 15;
        float4 v = *(const float4*)(xb + (size_t)c * Hc * Wcn + tq * 4);
        *(float4*)&Xs[c][tq * 4] = v;
    }
    __syncthreads();
    if (tid < 64) {
        float m = 0.f;
        for (int c = 0; c < 96; c++) m += Xs[c][tid];
        m *= (1.0f / 96.0f);
        float v = 0.f;
        for (int c = 0; c < 96; c++) { float d = Xs[c][tid] - m; v += d * d; }
        mu[tid] = m; inv[tid] = rsqrtf(v * (1.0f / 96.0f) + 1e-5f);
    }
    __syncthreads();
    #pragma unroll
    for (int i = 0; i < 24; i++) {
        int idx = i * 256 + tid; int c = idx >> 6, l = idx & 63;
        Xs[c][l] = (Xs[c][l] - mu[l]) * inv[l] * lws[c] + lbs[c];
    }
    __syncthreads();
    float acc[4][4] = {};
    #pragma unroll 8
    for (int k = 0; k < 96; k++) {
        float a0 = Ws[ty][k], a1 = Ws[ty + 16][k], a2 = Ws[ty + 32][k], a3 = Ws[ty + 48][k];
        float4 bv = *(float4*)&Xs[k][tx * 4];
        acc[0][0] += a0 * bv.x; acc[0][1] += a0 * bv.y; acc[0][2] += a0 * bv.z; acc[0][3] += a0 * bv.w;
        acc[1][0] += a1 * bv.x; acc[1][1] += a1 * bv.y; acc[1][2] += a1 * bv.z; acc[1][3] += a1 * bv.w;
        acc[2][0] += a2 * bv.x; acc[2][1] += a2 * bv.y; acc[2][2] += a2 * bv.z; acc[2][3] += a2 * bv.w;
        acc[3][0] += a3 * bv.x; acc[3][1] += a3 * bv.y; acc[3][2] += a3 * bv.z; acc[3][3] += a3 * bv.w;
    }
    if (et < 3) {
        #pragma unroll
        for (int i = 0; i < 4; i++) {
            float4 v = make_float4(acc[i][0], acc[i][1], acc[i][2], acc[i][3]);
            *(float4*)(xz + ((size_t)qb * DI + et * 64 + ty + 16 * i) * Lq + lt * 64 + tx * 4) = v;
        }
    } else {
        // transpose via LDS (reuse Ws storage), write zt[qb][l][d] coalesced
        float* zsp = &Ws[0][0];     // need 64*65 <= 64*100
        __syncthreads();
        #pragma unroll
        for (int i = 0; i < 4; i++) {
            int e = ty + 16 * i;
            #pragma unroll
            for (int j = 0; j < 4; j++) zsp[e * 65 + tx * 4 + j] = acc[i][j];
        }
        __syncthreads();
        int ez = tid & 63;
        #pragma unroll
        for (int it = 0; it < 16; it++) {
            int l = it * 4 + (tid >> 6);
            zt[((size_t)qb * Lq + lt * 64 + l) * DI + (et - 3) * 64 + ez] = zsp[ez * 65 + l];
        }
    }
}

// ---------------- causal depthwise conv (k=4)+bias+silu; out xi[qb][l][d] ---
__global__ void k_conv(const float* __restrict__ xz, const float* __restrict__ cw,
                       const float* __restrict__ cb, float* __restrict__ xi) {
    __shared__ float xs[64][68];    // d-tile 64 x (4 halo + 64 l)
    int lt = blockIdx.x;            // 64 l-tiles
    int dt = blockIdx.y;            // 3 d-tiles
    int qb = blockIdx.z; int q = qb >> 1;
    int tid = threadIdx.x;
    int l0 = lt * 64, d0 = dt * 64;
    #pragma unroll
    for (int it = 0; it < 5; it++) {
        int idx = it * 256 + tid;   // 64 rows x 17 float4 = 1088
        if (idx < 1088) {
            int row = idx / 17, q4 = idx % 17;
            if (l0 == 0 && q4 == 0) {
                *(float4*)&xs[row][0] = make_float4(0.f, 0.f, 0.f, 0.f);
            } else {
                float4 v = *(const float4*)(xz + ((size_t)qb * DI + d0 + row) * Lq + l0 - 4 + q4 * 4);
                *(float4*)&xs[row][q4 * 4] = v;
            }
        }
    }
    __syncthreads();
    int d = tid >> 2, lqi = tid & 3;
    int gd = q * DI + d0 + d;
    float w0 = cw[gd * 4 + 0], w1 = cw[gd * 4 + 1], w2 = cw[gd * 4 + 2], w3 = cw[gd * 4 + 3];
    float bias = cb[gd];
    float r[16];
    #pragma unroll
    for (int i = 0; i < 16; i++) {
        int c = 4 + lqi * 16 + i;
        float a = bias + w0 * xs[d][c - 3] + w1 * xs[d][c - 2] + w2 * xs[d][c - 1] + w3 * xs[d][c];
        r[i] = a / (1.f + expf(-a));
    }
    __syncthreads();
    float* ts = &xs[0][0];          // reuse as [64 d][65 l]
    #pragma unroll
    for (int i = 0; i < 16; i++) ts[d * 65 + lqi * 16 + i] = r[i];
    __syncthreads();
    int dz = tid & 63;
    #pragma unroll
    for (int it = 0; it < 16; it++) {
        int l = it * 4 + (tid >> 6);
        xi[((size_t)qb * Lq + l0 + l) * DI + d0 + dz] = ts[dz * 65 + l];
    }
}

__device__ __forceinline__ float softplusf(float x) {
    return fmaxf(x, 0.f) + log1pf(expf(-fabsf(x)));
}

// ---------------- x-projection GEMM -> dbl[qb][l][40] + fused delta ---------
// dbl cols: 0..5 dt, 8..23 B, 24..39 C
__global__ void k_xpproj(const float* __restrict__ xi, const float* __restrict__ xp_w,
                         const float* __restrict__ dt_w, const float* __restrict__ dt_b,
                         float* __restrict__ dbl, float* __restrict__ delta) {
    __shared__ float xt[64][65];    // [k][l]
    __shared__ float wq[48][68];    // [j][k]
    __shared__ float dts[64][8];
    int lt = blockIdx.x, qb = blockIdx.y, q = qb >> 1;
    int tid = threadIdx.x, tx = tid & 15, ty = tid >> 4;
    int l0 = lt * 64;
    float acc[3][4] = {};
    for (int ks = 0; ks < 3; ks++) {
        __syncthreads();
        #pragma unroll
        for (int it = 0; it < 4; it++) {
            int idx = it * 256 + tid; int l = idx >> 4, kq = idx & 15;
            float4 v = *(const float4*)(xi + ((size_t)qb * Lq + l0 + l) * DI + ks * 64 + kq * 4);
            xt[kq * 4 + 0][l] = v.x; xt[kq * 4 + 1][l] = v.y;
            xt[kq * 4 + 2][l] = v.z; xt[kq * 4 + 3][l] = v.w;
        }
        #pragma unroll
        for (int it = 0; it < 3; it++) {
            int idx = it * 256 + tid;
            if (idx < 608) {
                int j = idx >> 4, kq = idx & 15;
                float4 v = *(const float4*)(xp_w + ((size_t)q * 38 + j) * DI + ks * 64 + kq * 4);
                *(float4*)&wq[j][kq * 4] = v;
            }
        }
        __syncthreads();
        #pragma unroll 8
        for (int k = 0; k < 64; k++) {
            float x0 = xt[k][tx * 4], x1 = xt[k][tx * 4 + 1], x2 = xt[k][tx * 4 + 2], x3 = xt[k][tx * 4 + 3];
            float v0 = wq[ty][k], v1 = wq[ty + 16][k], v2 = wq[ty + 32][k];
            acc[0][0] += v0 * x0; acc[0][1] += v0 * x1; acc[0][2] += v0 * x2; acc[0][3] += v0 * x3;
            acc[1][0] += v1 * x0; acc[1][1] += v1 * x1; acc[1][2] += v1 * x2; acc[1][3] += v1 * x3;
            acc[2][0] += v2 * x0; acc[2][1] += v2 * x1; acc[2][2] += v2 * x2; acc[2][3] += v2 * x3;
        }
    }
    #pragma unroll
    for (int t = 0; t < 3; t++) {
        int j = ty + 16 * t;
        if (j < 38) {
            int col = j + (j >= 6 ? 2 : 0);
            #pragma unroll
            for (int i = 0; i < 4; i++)
                dbl[((size_t)qb * Lq + l0 + tx * 4 + i) * 40 + col] = acc[t][i];
        }
    }
    if (ty < 6) {
        #pragma unroll
        for (int i = 0; i < 4; i++) dts[tx * 4 + i][ty] = acc[0][i];
    }
    __syncthreads();
    if (tid < DI) {
        int d = tid;
        float dw[6];
        #pragma unroll
        for (int r = 0; r < 6; r++) dw[r] = dt_w[(size_t)(q * DI + d) * 6 + r];
        float db = dt_b[q * DI + d];
        for (int l = 0; l < 64; l++) {
            float t = db;
            #pragma unroll
            for (int r = 0; r < 6; r++) t += dts[l][r] * dw[r];
            delta[((size_t)qb * Lq + l0 + l) * DI + d] = softplusf(t);
        }
    }
}

// ---------------- scan pass 1: per-chunk decay product + local state --------
__global__ void k_scan1(const float* __restrict__ dbl, const float* __restrict__ delta,
                        const float* __restrict__ xi, const float* __restrict__ A_log,
                        float* __restrict__ P, float* __restrict__ Hl) {
    int qb = blockIdx.y; int q = qb >> 1;
    int ch = blockIdx.x;
    int d = threadIdx.x;
    float A[16], Pr[16], h[16];
    #pragma unroll
    for (int s = 0; s < 16; s++) {
        A[s] = -expf(A_log[((size_t)(q * DI + d)) * 16 + s]);
        Pr[s] = 1.f; h[s] = 0.f;
    }
    size_t lbase = (size_t)qb * Lq + ch * CH;
    for (int i = 0; i < CH; i++) {
        size_t l = lbase + i;
        const float* row = dbl + l * 40;
        float de = delta[l * DI + d];
        float dx = de * xi[l * DI + d];
        float Bv[16];
        *(float4*)&Bv[0]  = *(const float4*)(row + 8);
        *(float4*)&Bv[4]  = *(const float4*)(row + 12);
        *(float4*)&Bv[8]  = *(const float4*)(row + 16);
        *(float4*)&Bv[12] = *(const float4*)(row + 20);
        #pragma unroll
        for (int s = 0; s < 16; s++) {
            float dA = expf(de * A[s]);
            h[s] = dA * h[s] + dx * Bv[s];
            Pr[s] *= dA;
        }
    }
    size_t base = ((size_t)qb * NCH + ch) * 16;
    #pragma unroll
    for (int s = 0; s < 16; s++) {
        P[(base + s) * DI + d]  = Pr[s];
        Hl[(base + s) * DI + d] = h[s];
    }
}

// ---------------- scan pass 2: serial recombination; carry written into P ---
__global__ void k_scan2(float* __restrict__ P, const float* __restrict__ Hl) {
    int t = blockIdx.x * 256 + threadIdx.x;   // qb*3072 + sd
    int qb = t / (16 * DI);
    int sd = t % (16 * DI);
    float c = 0.f;
    for (int ch = 0; ch < NCH; ch++) {
        size_t idx = (size_t)(qb * NCH + ch) * (16 * DI) + sd;
        float p = P[idx], hl = Hl[idx];
        P[idx] = c;                 // carry in
        c = p * c + hl;
    }
}

// ---------------- scan pass 3: seeded rerun + y + gate; y aliases delta -----
__global__ void k_scan3(const float* __restrict__ dbl, float* deltaY,
                        const float* __restrict__ xi, const float* __restrict__ zt,
                        const float* __restrict__ A_log, const float* __restrict__ Dp,
                        const float* __restrict__ carry) {
    int qb = blockIdx.y; int q = qb >> 1;
    int ch = blockIdx.x;
    int d = threadIdx.x;
    float A[16], h[16];
    size_t cbase = (size_t)(qb * NCH + ch) * (16 * DI) + d;
    #pragma unroll
    for (int s = 0; s < 16; s++) {
        A[s] = -expf(A_log[((size_t)(q * DI + d)) * 16 + s]);
        h[s] = carry[cbase + (size_t)s * DI];
    }
    float dpv = Dp[q * DI + d];
    size_t lbase = (size_t)qb * Lq + ch * CH;
    for (int i = 0; i < CH; i++) {
        size_t l = lbase + i;
        const float* row = dbl + l * 40;
        float de = deltaY[l * DI + d];
        float xiv = xi[l * DI + d];
        float zv = zt[l * DI + d];
        float dx = de * xiv;
        float Bv[16], Cv[16];
        *(float4*)&Bv[0]  = *(const float4*)(row + 8);
        *(float4*)&Bv[4]  = *(const float4*)(row + 12);
        *(float4*)&Bv[8]  = *(const float4*)(row + 16);
        *(float4*)&Bv[12] = *(const float4*)(row + 20);
        *(float4*)&Cv[0]  = *(const float4*)(row + 24);
        *(float4*)&Cv[4]  = *(const float4*)(row + 28);
        *(float4*)&Cv[8]  = *(const float4*)(row + 32);
        *(float4*)&Cv[12] = *(const float4*)(row + 36);
        float y = 0.f;
        #pragma unroll
        for (int s = 0; s < 16; s++) {
            float dA = expf(de * A[s]);
            h[s] = dA * h[s] + dx * Bv[s];
            y += h[s] * Cv[s];
        }
        y += xiv * dpv;
        y *= zv / (1.f + expf(-zv));
        deltaY[l * DI + d] = y;     // overwrite delta (read-before-write per element)
    }
}

// ---------------- out-projection (y[l][d]) + residual add into xd -----------
__global__ void k_outproj_t(const float* __restrict__ yg, const float* __restrict__ out_w,
                            float* __restrict__ xd) {
    __shared__ float Ys[48][65];    // [k][l]
    __shared__ float Ws2[48][52];   // [c][k]
    int lt = blockIdx.x;            // 64 l-tiles (quadrant row)
    int ct = blockIdx.y;            // 2 c-tiles of 48
    int qb = blockIdx.z; int q = qb >> 1, b = qb & 1;
    int qr = q >> 1, qc = q & 1;
    int tid = threadIdx.x, tx = tid & 15, ty = tid >> 4;
    int l0 = lt * 64;
    float acc[3][4] = {};
    for (int ks = 0; ks < 4; ks++) {
        __syncthreads();
        #pragma unroll
        for (int it = 0; it < 3; it++) {
            int idx = it * 256 + tid;       // 64 l x 12 kq = 768
            if (idx < 768) {
                int l = idx / 12, kq = idx % 12;
                float4 v = *(const float4*)(yg + ((size_t)qb * Lq + l0 + l) * DI + ks * 48 + kq * 4);
                Ys[kq * 4 + 0][l] = v.x; Ys[kq * 4 + 1][l] = v.y;
                Ys[kq * 4 + 2][l] = v.z; Ys[kq * 4 + 3][l] = v.w;
            }
        }
        #pragma unroll
        for (int it = 0; it < 3; it++) {
            int idx = it * 256 + tid;       // 48 c x 12 = 576
            if (idx < 576) {
                int row = idx / 12, q4 = idx % 12;
                float4 v = *(const float4*)(out_w + ((size_t)(q * Cc + ct * 48 + row)) * DI + ks * 48 + q4 * 4);
                *(float4*)&Ws2[row][q4 * 4] = v;
            }
        }
        __syncthreads();
        #pragma unroll 4
        for (int kk = 0; kk < 48; kk++) {
            float y0 = Ys[kk][tx * 4], y1 = Ys[kk][tx * 4 + 1], y2 = Ys[kk][tx * 4 + 2], y3 = Ys[kk][tx * 4 + 3];
            float w0 = Ws2[ty][kk], w1 = Ws2[ty + 16][kk], w2 = Ws2[ty + 32][kk];
            acc[0][0] += w0 * y0; acc[0][1] += w0 * y1; acc[0][2] += w0 * y2; acc[0][3] += w0 * y3;
            acc[1][0] += w1 * y0; acc[1][1] += w1 * y1; acc[1][2] += w1 * y2; acc[1][3] += w1 * y3;
            acc[2][0] += w2 * y0; acc[2][1] += w2 * y1; acc[2][2] += w2 * y2; acc[2][3] += w2 * y3;
        }
    }
    #pragma unroll
    for (int i = 0; i < 3; i++) {
        int c = ct * 48 + ty + 16 * i;
        float* p = xd + ((size_t)(b * Cc + c) * Hc + qr * 64 + lt) * Wcn + qc * 64 + tx * 4;
        float4 v = *(float4*)p;
        v.x += acc[i][0]; v.y += acc[i][1]; v.z += acc[i][2]; v.w += acc[i][3];
        *(float4*)p = v;
    }
}

extern "C" void kernel_launch(void* const* d_in, const int* in_sizes, int n_in,
                              void* d_out, int out_size, void* d_ws, size_t ws_size,
                              hipStream_t stream) {
    const float* x     = (const float*)d_in[0];
    const float* ln_w  = (const float*)d_in[1];
    const float* ln_b  = (const float*)d_in[2];
    const float* in_w  = (const float*)d_in[3];
    const float* cw    = (const float*)d_in[4];
    const float* cb    = (const float*)d_in[5];
    const float* xp_w  = (const float*)d_in[6];
    const float* dt_w  = (const float*)d_in[7];
    const float* dt_b  = (const float*)d_in[8];
    const float* A_log = (const float*)d_in[9];
    const float* Dp    = (const float*)d_in[10];
    const float* out_w = (const float*)d_in[11];
    float* out = (float*)d_out;

    float* ws = (float*)d_ws;
    const size_t NPIX = (size_t)Bc * Cc * Hc * Wcn;      // 3,145,728
    float* M     = ws;                    // 16384
    float* MT    = M + 16384;             // 16384
    float* xm    = MT + 16384;            // NPIX   (aliased: P/carry spans xm+tmp)
    float* tmp   = xm + NPIX;             // NPIX
    float* xd    = tmp + NPIX;            // NPIX
    float* xz    = xd + NPIX;             // 8*192*4096 = 6,291,456 (aliased: Hl)
    float* xi    = xz + (size_t)8 * DI * Lq;     // 6,291,456
    float* zt    = xi + (size_t)8 * Lq * DI;     // 6,291,456
    float* dbl   = zt + (size_t)8 * Lq * DI;     // 8*4096*40 = 1,310,720
    float* delta = dbl + (size_t)8 * Lq * 40;    // 6,291,456 (aliased: y)
    float* P  = xm;    // 8*256*16*192 = 6,291,456 == xm+tmp exactly
    float* Hl = xz;

    k_dct_mat<<<128, 128, 0, stream>>>(M, MT);
    k_mask<<<dim3(Hc, Bc), Wcn, 0, stream>>>(x, xm);
    k_g128<<<dim3(192, 2, 2), 256, 0, stream>>>(M, 0, xm, 16384, tmp);     // DCT rows
    k_g128<<<dim3(192, 2, 2), 256, 0, stream>>>(tmp, 16384, MT, 0, xd);    // DCT cols
    k_inproj_t<<<dim3(64, 6, 8), 256, 0, stream>>>(xd, in_w, ln_w, ln_b, xz, zt);
    k_conv<<<dim3(64, 3, 8), 256, 0, stream>>>(xz, cw, cb, xi);
    k_xpproj<<<dim3(64, 8), 256, 0, stream>>>(xi, xp_w, dt_w, dt_b, dbl, delta);
    k_scan1<<<dim3(NCH, 8), DI, 0, stream>>>(dbl, delta, xi, A_log, P, Hl);
    k_scan2<<<96, 256, 0, stream>>>(P, Hl);
    k_scan3<<<dim3(NCH, 8), DI, 0, stream>>>(dbl, delta, xi, zt, A_log, Dp, P);
    k_outproj_t<<<dim3(64, 2, 8), 256, 0, stream>>>(delta, out_w, xd);
    k_g128<<<dim3(192, 2, 2), 256, 0, stream>>>(xd, 16384, M, 0, tmp);     // iDCT cols
    k_g128<<<dim3(192, 2, 2), 256, 0, stream>>>(MT, 0, tmp, 16384, out);   // iDCT rows
}

// Round 4
// 303.389 us; speedup vs baseline: 2.8863x; 1.1897x over previous
//
#include <hip/hip_runtime.h>
#include <math.h>

#define D_STATE 16
#define DT_RANK 6
constexpr int Bc = 2, Cc = 96, Hc = 128, Wcn = 128;
constexpr int DI = 192;       // d_inner
constexpr int Lq = 4096;      // 64*64 per quadrant
constexpr int CH = 16;        // scan chunk length
constexpr int NCH = Lq / CH;  // 256 chunks

// ---------------- DCT matrix build ------------------------------------------
__global__ void k_dct_mat(float* __restrict__ M, float* __restrict__ MT) {
    int i = blockIdx.x * blockDim.x + threadIdx.x; // 16384
    int n = i >> 7, k = i & 127;
    double v = cos(3.14159265358979323846 * (2.0 * k + 1.0) * n / 256.0) * sqrt(2.0 / 128.0);
    if (n == 0) v *= 0.70710678118654752440;
    M[n * 128 + k]  = (float)v;
    MT[k * 128 + n] = (float)v;
}

// ---------------- cosine-similarity mask ------------------------------------
__global__ void k_mask(const float* __restrict__ x, float* __restrict__ xm) {
    int b = blockIdx.y, h = blockIdx.x, w = threadIdx.x;
    const float* xb = x + (size_t)b * Cc * Hc * Wcn;
    float dot = 0.f, ss = 0.f, cs = 0.f;
    for (int c = 0; c < Cc; c++) {
        float xv = xb[(size_t)(c * Hc + h) * Wcn + w];
        float cv = xb[(size_t)(c * Hc + 64) * Wcn + 64];
        dot += xv * cv; ss += xv * xv; cs += cv * cv;
    }
    float sim = dot / (sqrtf(cs) * sqrtf(ss) + 1e-6f);
    float keep = (sim >= 0.7f) ? 1.0f : 0.0f;
    float* xo = xm + (size_t)b * Cc * Hc * Wcn;
    for (int c = 0; c < Cc; c++)
        xo[(size_t)(c * Hc + h) * Wcn + w] = keep * xb[(size_t)(c * Hc + h) * Wcn + w];
}

// ---------------- generic tiled 128x128x128 GEMM ----------------------------
__global__ void k_g128(const float* __restrict__ L, size_t lb,
                       const float* __restrict__ R, size_t rb,
                       float* __restrict__ D) {
    __shared__ float Ls[64][68];
    __shared__ float Rs[64][68];
    int bc = blockIdx.x;
    int r0 = blockIdx.y * 64, n0 = blockIdx.z * 64;
    const float* Lp = L + lb * bc;
    const float* Rp = R + rb * bc;
    float* Dq = D + (size_t)bc * 16384;
    int tid = threadIdx.x;
    int tx = tid & 15, ty = tid >> 4;
    float acc[4][4] = {};
    for (int ks = 0; ks < 2; ks++) {
        __syncthreads();
        #pragma unroll
        for (int i = 0; i < 4; i++) {
            int idx = i * 256 + tid;
            int row = idx >> 4, quad = idx & 15;
            float4 lv = *(const float4*)(Lp + (size_t)(r0 + row) * 128 + ks * 64 + quad * 4);
            *(float4*)&Ls[row][quad * 4] = lv;
            float4 rv = *(const float4*)(Rp + (size_t)(ks * 64 + row) * 128 + n0 + quad * 4);
            *(float4*)&Rs[row][quad * 4] = rv;
        }
        __syncthreads();
        #pragma unroll 8
        for (int j = 0; j < 64; j++) {
            float a0 = Ls[ty][j], a1 = Ls[ty + 16][j], a2 = Ls[ty + 32][j], a3 = Ls[ty + 48][j];
            float4 bv = *(float4*)&Rs[j][tx * 4];
            acc[0][0] += a0 * bv.x; acc[0][1] += a0 * bv.y; acc[0][2] += a0 * bv.z; acc[0][3] += a0 * bv.w;
            acc[1][0] += a1 * bv.x; acc[1][1] += a1 * bv.y; acc[1][2] += a1 * bv.z; acc[1][3] += a1 * bv.w;
            acc[2][0] += a2 * bv.x; acc[2][1] += a2 * bv.y; acc[2][2] += a2 * bv.z; acc[2][3] += a2 * bv.w;
            acc[3][0] += a3 * bv.x; acc[3][1] += a3 * bv.y; acc[3][2] += a3 * bv.z; acc[3][3] += a3 * bv.w;
        }
    }
    #pragma unroll
    for (int i = 0; i < 4; i++) {
        float4 v = make_float4(acc[i][0], acc[i][1], acc[i][2], acc[i][3]);
        *(float4*)(Dq + (size_t)(r0 + ty + 16 * i) * 128 + n0 + tx * 4) = v;
    }
}

// ---------------- in-projection, LN fused -----------------------------------
// et<3: xz[qb][e][l]  (x half, conv input);  et>=3: zt[qb][l][d] transposed
__global__ void k_inproj_t(const float* __restrict__ xd, const float* __restrict__ in_w,
                           const float* __restrict__ lnw, const float* __restrict__ lnb,
                           float* __restrict__ xz, float* __restrict__ zt) {
    __shared__ float Ws[64][100];   // e-tile 64 x K=96  (reused as transpose buf)
    __shared__ float Xs[96][68];    // c 96 x l-tile 64
    __shared__ float mu[64], inv[64], lws[96], lbs[96];
    int lt = blockIdx.x;            // 64 l-tiles (quadrant row)
    int et = blockIdx.y;            // 6 e-tiles
    int qb = blockIdx.z; int q = qb >> 1, b = qb & 1;
    int qr = q >> 1, qc = q & 1;
    int tid = threadIdx.x, tx = tid & 15, ty = tid >> 4;
    if (tid < 96) { lws[tid] = lnw[tid]; lbs[tid] = lnb[tid]; }
    #pragma unroll
    for (int i = 0; i < 6; i++) {
        int idx = i * 256 + tid; int e = idx / 24, kq = idx % 24;
        float4 v = *(const float4*)(in_w + ((size_t)(q * 384 + et * 64 + e)) * 96 + kq * 4);
        *(float4*)&Ws[e][kq * 4] = v;
    }
    const float* xb = xd + ((size_t)(b * Cc) * Hc + qr * 64 + lt) * Wcn + qc * 64;
    #pragma unroll
    for (int i = 0; i < 6; i++) {
        int idx = i * 256 + tid; int c = idx >> 4, tq = idx & 15;
        float4 v = *(const float4*)(xb + (size_t)c * Hc * Wcn + tq * 4);
        *(float4*)&Xs[c][tq * 4] = v;
    }
    __syncthreads();
    if (tid < 64) {
        float m = 0.f;
        for (int c = 0; c < 96; c++) m += Xs[c][tid];
        m *= (1.0f / 96.0f);
        float v = 0.f;
        for (int c = 0; c < 96; c++) { float d = Xs[c][tid] - m; v += d * d; }
        mu[tid] = m; inv[tid] = rsqrtf(v * (1.0f / 96.0f) + 1e-5f);
    }
    __syncthreads();
    #pragma unroll
    for (int i = 0; i < 24; i++) {
        int idx = i * 256 + tid; int c = idx >> 6, l = idx & 63;
        Xs[c][l] = (Xs[c][l] - mu[l]) * inv[l] * lws[c] + lbs[c];
    }
    __syncthreads();
    float acc[4][4] = {};
    #pragma unroll 8
    for (int k = 0; k < 96; k++) {
        float a0 = Ws[ty][k], a1 = Ws[ty + 16][k], a2 = Ws[ty + 32][k], a3 = Ws[ty + 48][k];
        float4 bv = *(float4*)&Xs[k][tx * 4];
        acc[0][0] += a0 * bv.x; acc[0][1] += a0 * bv.y; acc[0][2] += a0 * bv.z; acc[0][3] += a0 * bv.w;
        acc[1][0] += a1 * bv.x; acc[1][1] += a1 * bv.y; acc[1][2] += a1 * bv.z; acc[1][3] += a1 * bv.w;
        acc[2][0] += a2 * bv.x; acc[2][1] += a2 * bv.y; acc[2][2] += a2 * bv.z; acc[2][3] += a2 * bv.w;
        acc[3][0] += a3 * bv.x; acc[3][1] += a3 * bv.y; acc[3][2] += a3 * bv.z; acc[3][3] += a3 * bv.w;
    }
    if (et < 3) {
        #pragma unroll
        for (int i = 0; i < 4; i++) {
            float4 v = make_float4(acc[i][0], acc[i][1], acc[i][2], acc[i][3]);
            *(float4*)(xz + ((size_t)qb * DI + et * 64 + ty + 16 * i) * Lq + lt * 64 + tx * 4) = v;
        }
    } else {
        // transpose via LDS (reuse Ws storage), write zt[qb][l][d] coalesced
        float* zsp = &Ws[0][0];     // need 64*65 <= 64*100
        __syncthreads();
        #pragma unroll
        for (int i = 0; i < 4; i++) {
            int e = ty + 16 * i;
            #pragma unroll
            for (int j = 0; j < 4; j++) zsp[e * 65 + tx * 4 + j] = acc[i][j];
        }
        __syncthreads();
        int ez = tid & 63;
        #pragma unroll
        for (int it = 0; it < 16; it++) {
            int l = it * 4 + (tid >> 6);
            zt[((size_t)qb * Lq + lt * 64 + l) * DI + (et - 3) * 64 + ez] = zsp[ez * 65 + l];
        }
    }
}

// ---------------- causal depthwise conv (k=4)+bias+silu; out xi[qb][l][d] ---
__global__ void k_conv(const float* __restrict__ xz, const float* __restrict__ cw,
                       const float* __restrict__ cb, float* __restrict__ xi) {
    __shared__ float xs[64][68];    // d-tile 64 x (4 halo + 64 l)
    int lt = blockIdx.x;            // 64 l-tiles
    int dt = blockIdx.y;            // 3 d-tiles
    int qb = blockIdx.z; int q = qb >> 1;
    int tid = threadIdx.x;
    int l0 = lt * 64, d0 = dt * 64;
    #pragma unroll
    for (int it = 0; it < 5; it++) {
        int idx = it * 256 + tid;   // 64 rows x 17 float4 = 1088
        if (idx < 1088) {
            int row = idx / 17, q4 = idx % 17;
            if (l0 == 0 && q4 == 0) {
                *(float4*)&xs[row][0] = make_float4(0.f, 0.f, 0.f, 0.f);
            } else {
                float4 v = *(const float4*)(xz + ((size_t)qb * DI + d0 + row) * Lq + l0 - 4 + q4 * 4);
                *(float4*)&xs[row][q4 * 4] = v;
            }
        }
    }
    __syncthreads();
    int d = tid >> 2, lqi = tid & 3;
    int gd = q * DI + d0 + d;
    float w0 = cw[gd * 4 + 0], w1 = cw[gd * 4 + 1], w2 = cw[gd * 4 + 2], w3 = cw[gd * 4 + 3];
    float bias = cb[gd];
    float r[16];
    #pragma unroll
    for (int i = 0; i < 16; i++) {
        int c = 4 + lqi * 16 + i;
        float a = bias + w0 * xs[d][c - 3] + w1 * xs[d][c - 2] + w2 * xs[d][c - 1] + w3 * xs[d][c];
        r[i] = a / (1.f + __expf(-a));
    }
    __syncthreads();
    float* ts = &xs[0][0];          // reuse as [64 d][65 l]
    #pragma unroll
    for (int i = 0; i < 16; i++) ts[d * 65 + lqi * 16 + i] = r[i];
    __syncthreads();
    int dz = tid & 63;
    #pragma unroll
    for (int it = 0; it < 16; it++) {
        int l = it * 4 + (tid >> 6);
        xi[((size_t)qb * Lq + l0 + l) * DI + d0 + dz] = ts[dz * 65 + l];
    }
}

__device__ __forceinline__ float softplusf(float x) {
    return fmaxf(x, 0.f) + log1pf(__expf(-fabsf(x)));
}

// ---------------- x-projection GEMM -> dbl[qb][l][40] + fused delta ---------
// dbl cols: 0..5 dt, 8..23 B, 24..39 C
__global__ void k_xpproj(const float* __restrict__ xi, const float* __restrict__ xp_w,
                         const float* __restrict__ dt_w, const float* __restrict__ dt_b,
                         float* __restrict__ dbl, float* __restrict__ delta) {
    __shared__ float xt[64][65];    // [k][l]
    __shared__ float wq[48][68];    // [j][k]
    __shared__ float dts[64][8];
    int lt = blockIdx.x, qb = blockIdx.y, q = qb >> 1;
    int tid = threadIdx.x, tx = tid & 15, ty = tid >> 4;
    int l0 = lt * 64;
    float acc[3][4] = {};
    for (int ks = 0; ks < 3; ks++) {
        __syncthreads();
        #pragma unroll
        for (int it = 0; it < 4; it++) {
            int idx = it * 256 + tid; int l = idx >> 4, kq = idx & 15;
            float4 v = *(const float4*)(xi + ((size_t)qb * Lq + l0 + l) * DI + ks * 64 + kq * 4);
            xt[kq * 4 + 0][l] = v.x; xt[kq * 4 + 1][l] = v.y;
            xt[kq * 4 + 2][l] = v.z; xt[kq * 4 + 3][l] = v.w;
        }
        #pragma unroll
        for (int it = 0; it < 3; it++) {
            int idx = it * 256 + tid;
            if (idx < 608) {
                int j = idx >> 4, kq = idx & 15;
                float4 v = *(const float4*)(xp_w + ((size_t)q * 38 + j) * DI + ks * 64 + kq * 4);
                *(float4*)&wq[j][kq * 4] = v;
            }
        }
        __syncthreads();
        #pragma unroll 8
        for (int k = 0; k < 64; k++) {
            float x0 = xt[k][tx * 4], x1 = xt[k][tx * 4 + 1], x2 = xt[k][tx * 4 + 2], x3 = xt[k][tx * 4 + 3];
            float v0 = wq[ty][k], v1 = wq[ty + 16][k], v2 = wq[ty + 32][k];
            acc[0][0] += v0 * x0; acc[0][1] += v0 * x1; acc[0][2] += v0 * x2; acc[0][3] += v0 * x3;
            acc[1][0] += v1 * x0; acc[1][1] += v1 * x1; acc[1][2] += v1 * x2; acc[1][3] += v1 * x3;
            acc[2][0] += v2 * x0; acc[2][1] += v2 * x1; acc[2][2] += v2 * x2; acc[2][3] += v2 * x3;
        }
    }
    #pragma unroll
    for (int t = 0; t < 3; t++) {
        int j = ty + 16 * t;
        if (j < 38) {
            int col = j + (j >= 6 ? 2 : 0);
            #pragma unroll
            for (int i = 0; i < 4; i++)
                dbl[((size_t)qb * Lq + l0 + tx * 4 + i) * 40 + col] = acc[t][i];
        }
    }
    if (ty < 6) {
        #pragma unroll
        for (int i = 0; i < 4; i++) dts[tx * 4 + i][ty] = acc[0][i];
    }
    __syncthreads();
    if (tid < DI) {
        int d = tid;
        float dw[6];
        #pragma unroll
        for (int r = 0; r < 6; r++) dw[r] = dt_w[(size_t)(q * DI + d) * 6 + r];
        float db = dt_b[q * DI + d];
        for (int l = 0; l < 64; l++) {
            float t = db;
            #pragma unroll
            for (int r = 0; r < 6; r++) t += dts[l][r] * dw[r];
            delta[((size_t)qb * Lq + l0 + l) * DI + d] = softplusf(t);
        }
    }
}

// ---------------- scan pass 1: per-chunk decay product + local state --------
__global__ void k_scan1(const float* __restrict__ dbl, const float* __restrict__ delta,
                        const float* __restrict__ xi, const float* __restrict__ A_log,
                        float* __restrict__ P, float* __restrict__ Hl) {
    int qb = blockIdx.y; int q = qb >> 1;
    int ch = blockIdx.x;
    int d = threadIdx.x;
    float A[16], h[16];
    #pragma unroll
    for (int s = 0; s < 16; s++) {
        A[s] = -__expf(A_log[((size_t)(q * DI + d)) * 16 + s]);
        h[s] = 0.f;
    }
    float desum = 0.f;
    size_t lbase = (size_t)qb * Lq + ch * CH;
    for (int i = 0; i < CH; i++) {
        size_t l = lbase + i;
        const float* row = dbl + l * 40;
        float de = delta[l * DI + d];
        float dx = de * xi[l * DI + d];
        desum += de;
        float Bv[16];
        *(float4*)&Bv[0]  = *(const float4*)(row + 8);
        *(float4*)&Bv[4]  = *(const float4*)(row + 12);
        *(float4*)&Bv[8]  = *(const float4*)(row + 16);
        *(float4*)&Bv[12] = *(const float4*)(row + 20);
        #pragma unroll
        for (int s = 0; s < 16; s++) {
            float dA = __expf(de * A[s]);
            h[s] = dA * h[s] + dx * Bv[s];
        }
    }
    size_t base = ((size_t)qb * NCH + ch) * 16;
    #pragma unroll
    for (int s = 0; s < 16; s++) {
        P[(base + s) * DI + d]  = __expf(desum * A[s]);   // ∏ exp(δA) = exp(AΣδ)
        Hl[(base + s) * DI + d] = h[s];
    }
}

// ---------------- scan pass 2: serial recombination; carry written into P ---
__global__ void k_scan2(float* __restrict__ P, const float* __restrict__ Hl) {
    int t = blockIdx.x * 256 + threadIdx.x;   // qb*3072 + sd
    int qb = t / (16 * DI);
    int sd = t % (16 * DI);
    float c = 0.f;
    for (int ch = 0; ch < NCH; ch++) {
        size_t idx = (size_t)(qb * NCH + ch) * (16 * DI) + sd;
        float p = P[idx], hl = Hl[idx];
        P[idx] = c;                 // carry in
        c = p * c + hl;
    }
}

// ---------------- scan pass 3: seeded rerun + y + gate; y aliases delta -----
__global__ void k_scan3(const float* __restrict__ dbl, float* deltaY,
                        const float* __restrict__ xi, const float* __restrict__ zt,
                        const float* __restrict__ A_log, const float* __restrict__ Dp,
                        const float* __restrict__ carry) {
    int qb = blockIdx.y; int q = qb >> 1;
    int ch = blockIdx.x;
    int d = threadIdx.x;
    float A[16], h[16];
    size_t cbase = (size_t)(qb * NCH + ch) * (16 * DI) + d;
    #pragma unroll
    for (int s = 0; s < 16; s++) {
        A[s] = -__expf(A_log[((size_t)(q * DI + d)) * 16 + s]);
        h[s] = carry[cbase + (size_t)s * DI];
    }
    float dpv = Dp[q * DI + d];
    size_t lbase = (size_t)qb * Lq + ch * CH;
    for (int i = 0; i < CH; i++) {
        size_t l = lbase + i;
        const float* row = dbl + l * 40;
        float de = deltaY[l * DI + d];
        float xiv = xi[l * DI + d];
        float zv = zt[l * DI + d];
        float dx = de * xiv;
        float Bv[16], Cv[16];
        *(float4*)&Bv[0]  = *(const float4*)(row + 8);
        *(float4*)&Bv[4]  = *(const float4*)(row + 12);
        *(float4*)&Bv[8]  = *(const float4*)(row + 16);
        *(float4*)&Bv[12] = *(const float4*)(row + 20);
        *(float4*)&Cv[0]  = *(const float4*)(row + 24);
        *(float4*)&Cv[4]  = *(const float4*)(row + 28);
        *(float4*)&Cv[8]  = *(const float4*)(row + 32);
        *(float4*)&Cv[12] = *(const float4*)(row + 36);
        float y = 0.f;
        #pragma unroll
        for (int s = 0; s < 16; s++) {
            float dA = __expf(de * A[s]);
            h[s] = dA * h[s] + dx * Bv[s];
            y += h[s] * Cv[s];
        }
        y += xiv * dpv;
        y *= zv / (1.f + __expf(-zv));
        deltaY[l * DI + d] = y;     // overwrite delta (read-before-write per element)
    }
}

// ---------------- out-projection (y[l][d]) + residual add into xd -----------
__global__ void k_outproj_t(const float* __restrict__ yg, const float* __restrict__ out_w,
                            float* __restrict__ xd) {
    __shared__ float Ys[48][65];    // [k][l]
    __shared__ float Ws2[48][52];   // [c][k]
    int lt = blockIdx.x;            // 64 l-tiles (quadrant row)
    int ct = blockIdx.y;            // 2 c-tiles of 48
    int qb = blockIdx.z; int q = qb >> 1, b = qb & 1;
    int qr = q >> 1, qc = q & 1;
    int tid = threadIdx.x, tx = tid & 15, ty = tid >> 4;
    int l0 = lt * 64;
    float acc[3][4] = {};
    for (int ks = 0; ks < 4; ks++) {
        __syncthreads();
        #pragma unroll
        for (int it = 0; it < 3; it++) {
            int idx = it * 256 + tid;       // 64 l x 12 kq = 768
            if (idx < 768) {
                int l = idx / 12, kq = idx % 12;
                float4 v = *(const float4*)(yg + ((size_t)qb * Lq + l0 + l) * DI + ks * 48 + kq * 4);
                Ys[kq * 4 + 0][l] = v.x; Ys[kq * 4 + 1][l] = v.y;
                Ys[kq * 4 + 2][l] = v.z; Ys[kq * 4 + 3][l] = v.w;
            }
        }
        #pragma unroll
        for (int it = 0; it < 3; it++) {
            int idx = it * 256 + tid;       // 48 c x 12 = 576
            if (idx < 576) {
                int row = idx / 12, q4 = idx % 12;
                float4 v = *(const float4*)(out_w + ((size_t)(q * Cc + ct * 48 + row)) * DI + ks * 48 + q4 * 4);
                *(float4*)&Ws2[row][q4 * 4] = v;
            }
        }
        __syncthreads();
        #pragma unroll 4
        for (int kk = 0; kk < 48; kk++) {
            float y0 = Ys[kk][tx * 4], y1 = Ys[kk][tx * 4 + 1], y2 = Ys[kk][tx * 4 + 2], y3 = Ys[kk][tx * 4 + 3];
            float w0 = Ws2[ty][kk], w1 = Ws2[ty + 16][kk], w2 = Ws2[ty + 32][kk];
            acc[0][0] += w0 * y0; acc[0][1] += w0 * y1; acc[0][2] += w0 * y2; acc[0][3] += w0 * y3;
            acc[1][0] += w1 * y0; acc[1][1] += w1 * y1; acc[1][2] += w1 * y2; acc[1][3] += w1 * y3;
            acc[2][0] += w2 * y0; acc[2][1] += w2 * y1; acc[2][2] += w2 * y2; acc[2][3] += w2 * y3;
        }
    }
    #pragma unroll
    for (int i = 0; i < 3; i++) {
        int c = ct * 48 + ty + 16 * i;
        float* p = xd + ((size_t)(b * Cc + c) * Hc + qr * 64 + lt) * Wcn + qc * 64 + tx * 4;
        float4 v = *(float4*)p;
        v.x += acc[i][0]; v.y += acc[i][1]; v.z += acc[i][2]; v.w += acc[i][3];
        *(float4*)p = v;
    }
}

extern "C" void kernel_launch(void* const* d_in, const int* in_sizes, int n_in,
                              void* d_out, int out_size, void* d_ws, size_t ws_size,
                              hipStream_t stream) {
    const float* x     = (const float*)d_in[0];
    const float* ln_w  = (const float*)d_in[1];
    const float* ln_b  = (const float*)d_in[2];
    const float* in_w  = (const float*)d_in[3];
    const float* cw    = (const float*)d_in[4];
    const float* cb    = (const float*)d_in[5];
    const float* xp_w  = (const float*)d_in[6];
    const float* dt_w  = (const float*)d_in[7];
    const float* dt_b  = (const float*)d_in[8];
    const float* A_log = (const float*)d_in[9];
    const float* Dp    = (const float*)d_in[10];
    const float* out_w = (const float*)d_in[11];
    float* out = (float*)d_out;

    float* ws = (float*)d_ws;
    const size_t NPIX = (size_t)Bc * Cc * Hc * Wcn;      // 3,145,728
    float* M     = ws;                    // 16384
    float* MT    = M + 16384;             // 16384
    float* xm    = MT + 16384;            // NPIX   (aliased: P/carry spans xm+tmp)
    float* tmp   = xm + NPIX;             // NPIX
    float* xd    = tmp + NPIX;            // NPIX
    float* xz    = xd + NPIX;             // 8*192*4096 = 6,291,456 (aliased: Hl)
    float* xi    = xz + (size_t)8 * DI * Lq;     // 6,291,456
    float* zt    = xi + (size_t)8 * Lq * DI;     // 6,291,456
    float* dbl   = zt + (size_t)8 * Lq * DI;     // 8*4096*40 = 1,310,720
    float* delta = dbl + (size_t)8 * Lq * 40;    // 6,291,456 (aliased: y)
    float* P  = xm;    // 8*256*16*192 = 6,291,456 == xm+tmp exactly
    float* Hl = xz;

    k_dct_mat<<<128, 128, 0, stream>>>(M, MT);
    k_mask<<<dim3(Hc, Bc), Wcn, 0, stream>>>(x, xm);
    k_g128<<<dim3(192, 2, 2), 256, 0, stream>>>(M, 0, xm, 16384, tmp);     // DCT rows
    k_g128<<<dim3(192, 2, 2), 256, 0, stream>>>(tmp, 16384, MT, 0, xd);    // DCT cols
    k_inproj_t<<<dim3(64, 6, 8), 256, 0, stream>>>(xd, in_w, ln_w, ln_b, xz, zt);
    k_conv<<<dim3(64, 3, 8), 256, 0, stream>>>(xz, cw, cb, xi);
    k_xpproj<<<dim3(64, 8), 256, 0, stream>>>(xi, xp_w, dt_w, dt_b, dbl, delta);
    k_scan1<<<dim3(NCH, 8), DI, 0, stream>>>(dbl, delta, xi, A_log, P, Hl);
    k_scan2<<<96, 256, 0, stream>>>(P, Hl);
    k_scan3<<<dim3(NCH, 8), DI, 0, stream>>>(dbl, delta, xi, zt, A_log, Dp, P);
    k_outproj_t<<<dim3(64, 2, 8), 256, 0, stream>>>(delta, out_w, xd);
    k_g128<<<dim3(192, 2, 2), 256, 0, stream>>>(xd, 16384, M, 0, tmp);     // iDCT cols
    k_g128<<<dim3(192, 2, 2), 256, 0, stream>>>(MT, 0, tmp, 16384, out);   // iDCT rows
}

// Round 5
// 275.107 us; speedup vs baseline: 3.1830x; 1.1028x over previous
//
#include <hip/hip_runtime.h>
#include <math.h>

#define D_STATE 16
#define DT_RANK 6
constexpr int Bc = 2, Cc = 96, Hc = 128, Wcn = 128;
constexpr int DI = 192;       // d_inner
constexpr int Lq = 4096;      // 64*64 per quadrant
constexpr int CH = 32;        // scan chunk length
constexpr int NCH = Lq / CH;  // 128 chunks

// ---------------- DCT matrix build ------------------------------------------
__global__ void k_dct_mat(float* __restrict__ M, float* __restrict__ MT) {
    int i = blockIdx.x * blockDim.x + threadIdx.x; // 16384
    int n = i >> 7, k = i & 127;
    double v = cos(3.14159265358979323846 * (2.0 * k + 1.0) * n / 256.0) * sqrt(2.0 / 128.0);
    if (n == 0) v *= 0.70710678118654752440;
    M[n * 128 + k]  = (float)v;
    MT[k * 128 + n] = (float)v;
}

// ---------------- cosine-similarity mask ------------------------------------
__global__ void k_mask(const float* __restrict__ x, float* __restrict__ xm) {
    int b = blockIdx.y, h = blockIdx.x, w = threadIdx.x;
    const float* xb = x + (size_t)b * Cc * Hc * Wcn;
    float dot = 0.f, ss = 0.f, cs = 0.f;
    for (int c = 0; c < Cc; c++) {
        float xv = xb[(size_t)(c * Hc + h) * Wcn + w];
        float cv = xb[(size_t)(c * Hc + 64) * Wcn + 64];
        dot += xv * cv; ss += xv * xv; cs += cv * cv;
    }
    float sim = dot / (sqrtf(cs) * sqrtf(ss) + 1e-6f);
    float keep = (sim >= 0.7f) ? 1.0f : 0.0f;
    float* xo = xm + (size_t)b * Cc * Hc * Wcn;
    for (int c = 0; c < Cc; c++)
        xo[(size_t)(c * Hc + h) * Wcn + w] = keep * xb[(size_t)(c * Hc + h) * Wcn + w];
}

// ---------------- generic tiled 128x128x128 GEMM ----------------------------
__global__ void k_g128(const float* __restrict__ L, size_t lb,
                       const float* __restrict__ R, size_t rb,
                       float* __restrict__ D) {
    __shared__ float Ls[64][68];
    __shared__ float Rs[64][68];
    int bc = blockIdx.x;
    int r0 = blockIdx.y * 64, n0 = blockIdx.z * 64;
    const float* Lp = L + lb * bc;
    const float* Rp = R + rb * bc;
    float* Dq = D + (size_t)bc * 16384;
    int tid = threadIdx.x;
    int tx = tid & 15, ty = tid >> 4;
    float acc[4][4] = {};
    for (int ks = 0; ks < 2; ks++) {
        __syncthreads();
        #pragma unroll
        for (int i = 0; i < 4; i++) {
            int idx = i * 256 + tid;
            int row = idx >> 4, quad = idx & 15;
            float4 lv = *(const float4*)(Lp + (size_t)(r0 + row) * 128 + ks * 64 + quad * 4);
            *(float4*)&Ls[row][quad * 4] = lv;
            float4 rv = *(const float4*)(Rp + (size_t)(ks * 64 + row) * 128 + n0 + quad * 4);
            *(float4*)&Rs[row][quad * 4] = rv;
        }
        __syncthreads();
        #pragma unroll 8
        for (int j = 0; j < 64; j++) {
            float a0 = Ls[ty][j], a1 = Ls[ty + 16][j], a2 = Ls[ty + 32][j], a3 = Ls[ty + 48][j];
            float4 bv = *(float4*)&Rs[j][tx * 4];
            acc[0][0] += a0 * bv.x; acc[0][1] += a0 * bv.y; acc[0][2] += a0 * bv.z; acc[0][3] += a0 * bv.w;
            acc[1][0] += a1 * bv.x; acc[1][1] += a1 * bv.y; acc[1][2] += a1 * bv.z; acc[1][3] += a1 * bv.w;
            acc[2][0] += a2 * bv.x; acc[2][1] += a2 * bv.y; acc[2][2] += a2 * bv.z; acc[2][3] += a2 * bv.w;
            acc[3][0] += a3 * bv.x; acc[3][1] += a3 * bv.y; acc[3][2] += a3 * bv.z; acc[3][3] += a3 * bv.w;
        }
    }
    #pragma unroll
    for (int i = 0; i < 4; i++) {
        float4 v = make_float4(acc[i][0], acc[i][1], acc[i][2], acc[i][3]);
        *(float4*)(Dq + (size_t)(r0 + ty + 16 * i) * 128 + n0 + tx * 4) = v;
    }
}

// ---------------- in-projection, LN fused, all 6 e-tiles per block ----------
__global__ void k_inproj_t(const float* __restrict__ xd, const float* __restrict__ in_w,
                           const float* __restrict__ lnw, const float* __restrict__ lnb,
                           float* __restrict__ xz, float* __restrict__ zt) {
    __shared__ float Ws[64][100];   // e-tile 64 x K=96  (reused as transpose buf)
    __shared__ float Xs[96][68];    // c 96 x l-tile 64
    __shared__ float red[4][64];
    __shared__ float mu[64], inv[64], lws[96], lbs[96];
    int lt = blockIdx.x;            // 64 l-tiles (quadrant row)
    int qb = blockIdx.y; int q = qb >> 1, b = qb & 1;
    int qr = q >> 1, qc = q & 1;
    int tid = threadIdx.x, tx = tid & 15, ty = tid >> 4;
    if (tid < 96) { lws[tid] = lnw[tid]; lbs[tid] = lnb[tid]; }
    const float* xb = xd + ((size_t)(b * Cc) * Hc + qr * 64 + lt) * Wcn + qc * 64;
    #pragma unroll
    for (int i = 0; i < 6; i++) {
        int idx = i * 256 + tid; int c = idx >> 4, tq = idx & 15;
        *(float4*)&Xs[c][tq * 4] = *(const float4*)(xb + (size_t)c * Hc * Wcn + tq * 4);
    }
    __syncthreads();
    int l = tid & 63, g = tid >> 6;
    {
        float m = 0.f;
        #pragma unroll
        for (int c = 0; c < 24; c++) m += Xs[g * 24 + c][l];
        red[g][l] = m;
    }
    __syncthreads();
    if (tid < 64) mu[tid] = (red[0][tid] + red[1][tid] + red[2][tid] + red[3][tid]) * (1.f / 96.f);
    __syncthreads();
    {
        float v = 0.f, m = mu[l];
        #pragma unroll
        for (int c = 0; c < 24; c++) { float d0 = Xs[g * 24 + c][l] - m; v += d0 * d0; }
        red[g][l] = v;
    }
    __syncthreads();
    if (tid < 64)
        inv[tid] = rsqrtf((red[0][tid] + red[1][tid] + red[2][tid] + red[3][tid]) * (1.f / 96.f) + 1e-5f);
    __syncthreads();
    #pragma unroll
    for (int i = 0; i < 24; i++) {
        int idx = i * 256 + tid; int c = idx >> 6, ll = idx & 63;
        Xs[c][ll] = (Xs[c][ll] - mu[ll]) * inv[ll] * lws[c] + lbs[c];
    }
    for (int et = 0; et < 6; et++) {
        __syncthreads();
        #pragma unroll
        for (int i = 0; i < 6; i++) {
            int idx = i * 256 + tid; int e = idx / 24, kq = idx % 24;
            *(float4*)&Ws[e][kq * 4] =
                *(const float4*)(in_w + ((size_t)(q * 384 + et * 64 + e)) * 96 + kq * 4);
        }
        __syncthreads();
        float acc[4][4] = {};
        #pragma unroll 8
        for (int k = 0; k < 96; k++) {
            float a0 = Ws[ty][k], a1 = Ws[ty + 16][k], a2 = Ws[ty + 32][k], a3 = Ws[ty + 48][k];
            float4 bv = *(float4*)&Xs[k][tx * 4];
            acc[0][0] += a0 * bv.x; acc[0][1] += a0 * bv.y; acc[0][2] += a0 * bv.z; acc[0][3] += a0 * bv.w;
            acc[1][0] += a1 * bv.x; acc[1][1] += a1 * bv.y; acc[1][2] += a1 * bv.z; acc[1][3] += a1 * bv.w;
            acc[2][0] += a2 * bv.x; acc[2][1] += a2 * bv.y; acc[2][2] += a2 * bv.z; acc[2][3] += a2 * bv.w;
            acc[3][0] += a3 * bv.x; acc[3][1] += a3 * bv.y; acc[3][2] += a3 * bv.z; acc[3][3] += a3 * bv.w;
        }
        if (et < 3) {
            #pragma unroll
            for (int i = 0; i < 4; i++) {
                float4 v = make_float4(acc[i][0], acc[i][1], acc[i][2], acc[i][3]);
                *(float4*)(xz + ((size_t)qb * DI + et * 64 + ty + 16 * i) * Lq + lt * 64 + tx * 4) = v;
            }
        } else {
            float* zsp = &Ws[0][0];     // reuse Ws as 64x65 transpose buffer
            __syncthreads();
            #pragma unroll
            for (int i = 0; i < 4; i++) {
                int e = ty + 16 * i;
                #pragma unroll
                for (int j = 0; j < 4; j++) zsp[e * 65 + tx * 4 + j] = acc[i][j];
            }
            __syncthreads();
            int ez = tid & 63;
            #pragma unroll
            for (int it = 0; it < 16; it++) {
                int ll = it * 4 + (tid >> 6);
                zt[((size_t)qb * Lq + lt * 64 + ll) * DI + (et - 3) * 64 + ez] = zsp[ez * 65 + ll];
            }
        }
    }
}

// ---------------- causal depthwise conv (k=4)+bias+silu; out xi[qb][l][d] ---
__global__ void k_conv(const float* __restrict__ xz, const float* __restrict__ cw,
                       const float* __restrict__ cb, float* __restrict__ xi) {
    __shared__ float xs[64][68];    // d-tile 64 x (4 halo + 64 l)
    int lt = blockIdx.x;            // 64 l-tiles
    int dt = blockIdx.y;            // 3 d-tiles
    int qb = blockIdx.z; int q = qb >> 1;
    int tid = threadIdx.x;
    int l0 = lt * 64, d0 = dt * 64;
    #pragma unroll
    for (int it = 0; it < 5; it++) {
        int idx = it * 256 + tid;   // 64 rows x 17 float4 = 1088
        if (idx < 1088) {
            int row = idx / 17, q4 = idx % 17;
            if (l0 == 0 && q4 == 0) {
                *(float4*)&xs[row][0] = make_float4(0.f, 0.f, 0.f, 0.f);
            } else {
                float4 v = *(const float4*)(xz + ((size_t)qb * DI + d0 + row) * Lq + l0 - 4 + q4 * 4);
                *(float4*)&xs[row][q4 * 4] = v;
            }
        }
    }
    __syncthreads();
    int d = tid >> 2, lqi = tid & 3;
    int gd = q * DI + d0 + d;
    float w0 = cw[gd * 4 + 0], w1 = cw[gd * 4 + 1], w2 = cw[gd * 4 + 2], w3 = cw[gd * 4 + 3];
    float bias = cb[gd];
    float r[16];
    #pragma unroll
    for (int i = 0; i < 16; i++) {
        int c = 4 + lqi * 16 + i;
        float a = bias + w0 * xs[d][c - 3] + w1 * xs[d][c - 2] + w2 * xs[d][c - 1] + w3 * xs[d][c];
        r[i] = a / (1.f + __expf(-a));
    }
    __syncthreads();
    float* ts = &xs[0][0];          // reuse as [64 d][65 l]
    #pragma unroll
    for (int i = 0; i < 16; i++) ts[d * 65 + lqi * 16 + i] = r[i];
    __syncthreads();
    int dz = tid & 63;
    #pragma unroll
    for (int it = 0; it < 16; it++) {
        int l = it * 4 + (tid >> 6);
        xi[((size_t)qb * Lq + l0 + l) * DI + d0 + dz] = ts[dz * 65 + l];
    }
}

__device__ __forceinline__ float softplusf(float x) {
    return fmaxf(x, 0.f) + __logf(1.f + __expf(-fabsf(x)));
}

// ---------------- x-projection GEMM -> dbl[qb][l][40] + fused delta ---------
// dbl cols: 0..5 dt, 8..23 B, 24..39 C.  LDS tile [l][k] (no transpose).
__global__ void k_xpproj(const float* __restrict__ xi, const float* __restrict__ xp_w,
                         const float* __restrict__ dt_w, const float* __restrict__ dt_b,
                         float* __restrict__ dbl, float* __restrict__ delta) {
    __shared__ float xt[64][65];    // [l][k-chunk]
    __shared__ float wq[48][68];    // [j][k]
    __shared__ float dts[64][9];
    int lt = blockIdx.x, qb = blockIdx.y, q = qb >> 1;
    int tid = threadIdx.x, tx = tid & 15, ty = tid >> 4;
    int l0 = lt * 64;
    float acc[3][4] = {};
    for (int ks = 0; ks < 3; ks++) {
        __syncthreads();
        #pragma unroll
        for (int it = 0; it < 4; it++) {
            int idx = it * 256 + tid; int l = idx >> 4, kq = idx & 15;
            *(float4*)&xt[l][kq * 4] =
                *(const float4*)(xi + ((size_t)qb * Lq + l0 + l) * DI + ks * 64 + kq * 4);
        }
        #pragma unroll
        for (int it = 0; it < 3; it++) {
            int idx = it * 256 + tid;
            if (idx < 608) {
                int j = idx >> 4, kq = idx & 15;
                *(float4*)&wq[j][kq * 4] =
                    *(const float4*)(xp_w + ((size_t)q * 38 + j) * DI + ks * 64 + kq * 4);
            }
        }
        __syncthreads();
        #pragma unroll 8
        for (int k = 0; k < 64; k++) {
            float x0 = xt[tx * 4 + 0][k], x1 = xt[tx * 4 + 1][k];
            float x2 = xt[tx * 4 + 2][k], x3 = xt[tx * 4 + 3][k];
            float v0 = wq[ty][k], v1 = wq[ty + 16][k], v2 = wq[ty + 32][k];
            acc[0][0] += v0 * x0; acc[0][1] += v0 * x1; acc[0][2] += v0 * x2; acc[0][3] += v0 * x3;
            acc[1][0] += v1 * x0; acc[1][1] += v1 * x1; acc[1][2] += v1 * x2; acc[1][3] += v1 * x3;
            acc[2][0] += v2 * x0; acc[2][1] += v2 * x1; acc[2][2] += v2 * x2; acc[2][3] += v2 * x3;
        }
    }
    #pragma unroll
    for (int t = 0; t < 3; t++) {
        int j = ty + 16 * t;
        if (j < 38) {
            int col = j + (j >= 6 ? 2 : 0);
            #pragma unroll
            for (int i = 0; i < 4; i++)
                dbl[((size_t)qb * Lq + l0 + tx * 4 + i) * 40 + col] = acc[t][i];
        }
    }
    if (ty < 6) {
        #pragma unroll
        for (int i = 0; i < 4; i++) dts[tx * 4 + i][ty] = acc[0][i];
    }
    __syncthreads();
    if (tid < DI) {
        int d = tid;
        float dw[6];
        #pragma unroll
        for (int r = 0; r < 6; r++) dw[r] = dt_w[(size_t)(q * DI + d) * 6 + r];
        float db = dt_b[q * DI + d];
        for (int l = 0; l < 64; l++) {
            float t = db;
            #pragma unroll
            for (int r = 0; r < 6; r++) t += dts[l][r] * dw[r];
            delta[((size_t)qb * Lq + l0 + l) * DI + d] = softplusf(t);
        }
    }
}

// ---------------- scan pass 1: per-chunk decay product + local state --------
__global__ void k_scan1(const float* __restrict__ dbl, const float* __restrict__ delta,
                        const float* __restrict__ xi, const float* __restrict__ A_log,
                        float* __restrict__ P, float* __restrict__ Hl) {
    int qb = blockIdx.y; int q = qb >> 1;
    int ch = blockIdx.x;
    int d = threadIdx.x;
    float A[16], h[16];
    #pragma unroll
    for (int s = 0; s < 16; s++) {
        A[s] = -__expf(A_log[((size_t)(q * DI + d)) * 16 + s]);
        h[s] = 0.f;
    }
    float desum = 0.f;
    size_t lbase = (size_t)qb * Lq + ch * CH;
    for (int i = 0; i < CH; i++) {
        size_t l = lbase + i;
        const float* row = dbl + l * 40;
        float de = delta[l * DI + d];
        float dx = de * xi[l * DI + d];
        desum += de;
        float Bv[16];
        *(float4*)&Bv[0]  = *(const float4*)(row + 8);
        *(float4*)&Bv[4]  = *(const float4*)(row + 12);
        *(float4*)&Bv[8]  = *(const float4*)(row + 16);
        *(float4*)&Bv[12] = *(const float4*)(row + 20);
        #pragma unroll
        for (int s = 0; s < 16; s++) {
            float dA = __expf(de * A[s]);
            h[s] = dA * h[s] + dx * Bv[s];
        }
    }
    size_t base = ((size_t)qb * NCH + ch) * 16;
    #pragma unroll
    for (int s = 0; s < 16; s++) {
        P[(base + s) * DI + d]  = __expf(desum * A[s]);   // ∏ exp(δA) = exp(AΣδ)
        Hl[(base + s) * DI + d] = h[s];
    }
}

// ---------------- scan pass 2: serial recombination; carry written into P ---
__global__ void k_scan2(float* __restrict__ P, const float* __restrict__ Hl) {
    int t = blockIdx.x * 256 + threadIdx.x;   // qb*3072 + sd
    int qb = t / (16 * DI);
    int sd = t % (16 * DI);
    float c = 0.f;
    for (int ch = 0; ch < NCH; ch++) {
        size_t idx = (size_t)(qb * NCH + ch) * (16 * DI) + sd;
        float p = P[idx], hl = Hl[idx];
        P[idx] = c;                 // carry in
        c = p * c + hl;
    }
}

// ---------------- scan pass 3: seeded rerun + y + gate; y aliases delta -----
__global__ void k_scan3(const float* __restrict__ dbl, float* deltaY,
                        const float* __restrict__ xi, const float* __restrict__ zt,
                        const float* __restrict__ A_log, const float* __restrict__ Dp,
                        const float* __restrict__ carry) {
    int qb = blockIdx.y; int q = qb >> 1;
    int ch = blockIdx.x;
    int d = threadIdx.x;
    float A[16], h[16];
    size_t cbase = (size_t)(qb * NCH + ch) * (16 * DI) + d;
    #pragma unroll
    for (int s = 0; s < 16; s++) {
        A[s] = -__expf(A_log[((size_t)(q * DI + d)) * 16 + s]);
        h[s] = carry[cbase + (size_t)s * DI];
    }
    float dpv = Dp[q * DI + d];
    size_t lbase = (size_t)qb * Lq + ch * CH;
    for (int i = 0; i < CH; i++) {
        size_t l = lbase + i;
        const float* row = dbl + l * 40;
        float de = deltaY[l * DI + d];
        float xiv = xi[l * DI + d];
        float zv = zt[l * DI + d];
        float dx = de * xiv;
        float Bv[16], Cv[16];
        *(float4*)&Bv[0]  = *(const float4*)(row + 8);
        *(float4*)&Bv[4]  = *(const float4*)(row + 12);
        *(float4*)&Bv[8]  = *(const float4*)(row + 16);
        *(float4*)&Bv[12] = *(const float4*)(row + 20);
        *(float4*)&Cv[0]  = *(const float4*)(row + 24);
        *(float4*)&Cv[4]  = *(const float4*)(row + 28);
        *(float4*)&Cv[8]  = *(const float4*)(row + 32);
        *(float4*)&Cv[12] = *(const float4*)(row + 36);
        float y = 0.f;
        #pragma unroll
        for (int s = 0; s < 16; s++) {
            float dA = __expf(de * A[s]);
            h[s] = dA * h[s] + dx * Bv[s];
            y += h[s] * Cv[s];
        }
        y += xiv * dpv;
        y *= zv / (1.f + __expf(-zv));
        deltaY[l * DI + d] = y;     // overwrite delta (read-before-write per element)
    }
}

// ---------------- out-projection (y[l][d]) + residual add into xd -----------
__global__ void k_outproj_t(const float* __restrict__ yg, const float* __restrict__ out_w,
                            float* __restrict__ xd) {
    __shared__ float Ys[48][65];    // [k][l]
    __shared__ float Ws2[48][52];   // [c][k]
    int lt = blockIdx.x;            // 64 l-tiles (quadrant row)
    int ct = blockIdx.y;            // 2 c-tiles of 48
    int qb = blockIdx.z; int q = qb >> 1, b = qb & 1;
    int qr = q >> 1, qc = q & 1;
    int tid = threadIdx.x, tx = tid & 15, ty = tid >> 4;
    int l0 = lt * 64;
    float acc[3][4] = {};
    for (int ks = 0; ks < 4; ks++) {
        __syncthreads();
        #pragma unroll
        for (int it = 0; it < 3; it++) {
            int idx = it * 256 + tid;       // 64 l x 12 kq = 768
            if (idx < 768) {
                int l = idx / 12, kq = idx % 12;
                float4 v = *(const float4*)(yg + ((size_t)qb * Lq + l0 + l) * DI + ks * 48 + kq * 4);
                Ys[kq * 4 + 0][l] = v.x; Ys[kq * 4 + 1][l] = v.y;
                Ys[kq * 4 + 2][l] = v.z; Ys[kq * 4 + 3][l] = v.w;
            }
        }
        #pragma unroll
        for (int it = 0; it < 3; it++) {
            int idx = it * 256 + tid;       // 48 c x 12 = 576
            if (idx < 576) {
                int row = idx / 12, q4 = idx % 12;
                float4 v = *(const float4*)(out_w + ((size_t)(q * Cc + ct * 48 + row)) * DI + ks * 48 + q4 * 4);
                *(float4*)&Ws2[row][q4 * 4] = v;
            }
        }
        __syncthreads();
        #pragma unroll 4
        for (int kk = 0; kk < 48; kk++) {
            float y0 = Ys[kk][tx * 4], y1 = Ys[kk][tx * 4 + 1], y2 = Ys[kk][tx * 4 + 2], y3 = Ys[kk][tx * 4 + 3];
            float w0 = Ws2[ty][kk], w1 = Ws2[ty + 16][kk], w2 = Ws2[ty + 32][kk];
            acc[0][0] += w0 * y0; acc[0][1] += w0 * y1; acc[0][2] += w0 * y2; acc[0][3] += w0 * y3;
            acc[1][0] += w1 * y0; acc[1][1] += w1 * y1; acc[1][2] += w1 * y2; acc[1][3] += w1 * y3;
            acc[2][0] += w2 * y0; acc[2][1] += w2 * y1; acc[2][2] += w2 * y2; acc[2][3] += w2 * y3;
        }
    }
    #pragma unroll
    for (int i = 0; i < 3; i++) {
        int c = ct * 48 + ty + 16 * i;
        float* p = xd + ((size_t)(b * Cc + c) * Hc + qr * 64 + lt) * Wcn + qc * 64 + tx * 4;
        float4 v = *(float4*)p;
        v.x += acc[i][0]; v.y += acc[i][1]; v.z += acc[i][2]; v.w += acc[i][3];
        *(float4*)p = v;
    }
}

extern "C" void kernel_launch(void* const* d_in, const int* in_sizes, int n_in,
                              void* d_out, int out_size, void* d_ws, size_t ws_size,
                              hipStream_t stream) {
    const float* x     = (const float*)d_in[0];
    const float* ln_w  = (const float*)d_in[1];
    const float* ln_b  = (const float*)d_in[2];
    const float* in_w  = (const float*)d_in[3];
    const float* cw    = (const float*)d_in[4];
    const float* cb    = (const float*)d_in[5];
    const float* xp_w  = (const float*)d_in[6];
    const float* dt_w  = (const float*)d_in[7];
    const float* dt_b  = (const float*)d_in[8];
    const float* A_log = (const float*)d_in[9];
    const float* Dp    = (const float*)d_in[10];
    const float* out_w = (const float*)d_in[11];
    float* out = (float*)d_out;

    float* ws = (float*)d_ws;
    const size_t NPIX = (size_t)Bc * Cc * Hc * Wcn;      // 3,145,728
    float* M     = ws;                    // 16384
    float* MT    = M + 16384;             // 16384
    float* xm    = MT + 16384;            // NPIX  (aliased: P/carry — 8*128*16*192 = NPIX exactly)
    float* tmp   = xm + NPIX;             // NPIX  (aliased: Hl)
    float* xd    = tmp + NPIX;            // NPIX
    float* xz    = xd + NPIX;             // 8*192*4096
    float* xi    = xz + (size_t)8 * DI * Lq;
    float* zt    = xi + (size_t)8 * Lq * DI;
    float* dbl   = zt + (size_t)8 * Lq * DI;     // 8*4096*40
    float* delta = dbl + (size_t)8 * Lq * 40;    // (aliased: y)
    float* P  = xm;
    float* Hl = tmp;

    k_dct_mat<<<128, 128, 0, stream>>>(M, MT);
    k_mask<<<dim3(Hc, Bc), Wcn, 0, stream>>>(x, xm);
    k_g128<<<dim3(192, 2, 2), 256, 0, stream>>>(M, 0, xm, 16384, tmp);     // DCT rows
    k_g128<<<dim3(192, 2, 2), 256, 0, stream>>>(tmp, 16384, MT, 0, xd);    // DCT cols
    k_inproj_t<<<dim3(64, 8), 256, 0, stream>>>(xd, in_w, ln_w, ln_b, xz, zt);
    k_conv<<<dim3(64, 3, 8), 256, 0, stream>>>(xz, cw, cb, xi);
    k_xpproj<<<dim3(64, 8), 256, 0, stream>>>(xi, xp_w, dt_w, dt_b, dbl, delta);
    k_scan1<<<dim3(NCH, 8), DI, 0, stream>>>(dbl, delta, xi, A_log, P, Hl);
    k_scan2<<<96, 256, 0, stream>>>(P, Hl);
    k_scan3<<<dim3(NCH, 8), DI, 0, stream>>>(dbl, delta, xi, zt, A_log, Dp, P);
    k_outproj_t<<<dim3(64, 2, 8), 256, 0, stream>>>(delta, out_w, xd);
    k_g128<<<dim3(192, 2, 2), 256, 0, stream>>>(xd, 16384, M, 0, tmp);     // iDCT cols
    k_g128<<<dim3(192, 2, 2), 256, 0, stream>>>(MT, 0, tmp, 16384, out);   // iDCT rows
}